// Round 3
// baseline (1403.679 us; speedup 1.0000x reference)
//
#include <hip/hip_runtime.h>

#define NEG_SLOPE 0.2f
#define BKT_SHIFT 7
#define BKT_NODES 128
#define BKT_CAP 6144

// ---------------- Kernel: node prep layer 1 ----------------
__global__ void k_node1(const float* __restrict__ x, const int* __restrict__ type_ids,
                        const float* __restrict__ type_emb, const float* __restrict__ W1,
                        const float* __restrict__ a_src1, const float* __restrict__ a_dst1,
                        float* __restrict__ h1, float* __restrict__ als1, float* __restrict__ ald1,
                        int N)
{
    int node = blockIdx.x * 4 + (threadIdx.x >> 6);
    int j = threadIdx.x & 63;
    if (node >= N) return;

    float xin[21];
#pragma unroll
    for (int k = 0; k < 5; k++) xin[k] = x[node * 5 + k];
    int t = type_ids[node];
#pragma unroll
    for (int k = 0; k < 16; k++) xin[5 + k] = type_emb[t * 16 + k];

    float h = 0.f;
#pragma unroll
    for (int k = 0; k < 21; k++) h += xin[k] * W1[k * 64 + j];
    h1[node * 64 + j] = h;

    int head = j >> 5, lane = j & 31;
    float ps = h * a_src1[head * 32 + lane];
    float pd = h * a_dst1[head * 32 + lane];
#pragma unroll
    for (int m = 16; m >= 1; m >>= 1) { ps += __shfl_xor(ps, m); pd += __shfl_xor(pd, m); }
    if (lane == 0) { als1[node * 2 + head] = ps; ald1[node * 2 + head] = pd; }
}

// ---------------- CSR build, phase A: bucket append ----------------
// Append src|(dlow<<20) to bucket (dst>>7). Cursor-ordered appends -> full-line writes.
__global__ void k_bucket(const int* __restrict__ ei, unsigned int* __restrict__ pk,
                         int* __restrict__ bcnt, int E, int N)
{
    int i = blockIdx.x * 256 + threadIdx.x;
    int s, d;
    if (i < E) { s = ei[i]; d = ei[E + i]; }
    else if (i < E + N) { s = d = i - E; }   // self-loop
    else return;
    int b = d >> BKT_SHIFT;
    int pos = atomicAdd(&bcnt[b], 1);
    if (pos < BKT_CAP)
        pk[(size_t)b * BKT_CAP + pos] = (unsigned)s | ((unsigned)(d & (BKT_NODES - 1)) << 20);
}

// ---------------- CSR build: bucket-start scan (NBKT <= 1024) ----------------
__global__ void k_bscan(const int* __restrict__ bcnt, int* __restrict__ bstart, int NBKT)
{
    __shared__ int sh[1024];
    int t = threadIdx.x;
    int v = (t < NBKT) ? min(bcnt[t], BKT_CAP) : 0;
    sh[t] = v;
    __syncthreads();
    for (int off = 1; off < 1024; off <<= 1) {
        int xv = (t >= off) ? sh[t - off] : 0;
        __syncthreads();
        sh[t] += xv;
        __syncthreads();
    }
    if (t < NBKT) bstart[t] = sh[t] - v;
}

// ---------------- CSR build, phase B: per-bucket count/scan/scatter ----------------
// One 256-thread block per bucket. Writes rs/cur and scatters ssrc into a
// contiguous ~17KB region (L2-resident -> full-line writeback).
__global__ void k_build(const unsigned int* __restrict__ pk, const int* __restrict__ bcnt,
                        const int* __restrict__ bstart, int* __restrict__ rs,
                        int* __restrict__ cur, int* __restrict__ ssrc, int N)
{
    __shared__ int cnt[BKT_NODES];
    __shared__ int base[BKT_NODES];
    int b = blockIdx.x;
    int t = threadIdx.x;
    int nb = min(bcnt[b], BKT_CAP);
    int bs = bstart[b];
    if (t < BKT_NODES) cnt[t] = 0;
    __syncthreads();
    const unsigned int* mypk = pk + (size_t)b * BKT_CAP;
    for (int e = t; e < nb; e += 256)
        atomicAdd(&cnt[mypk[e] >> 20], 1);
    __syncthreads();
    if (t < BKT_NODES) base[t] = cnt[t];
    __syncthreads();
    for (int off = 1; off < BKT_NODES; off <<= 1) {
        int v = (t < BKT_NODES && t >= off) ? base[t - off] : 0;
        __syncthreads();
        if (t < BKT_NODES) base[t] += v;
        __syncthreads();
    }
    if (t < BKT_NODES) {
        int ex = base[t] - cnt[t];       // exclusive
        base[t] = ex;                    // becomes cursor
        int node = (b << BKT_SHIFT) + t;
        if (node < N) { rs[node] = bs + ex; cur[node] = bs + ex + cnt[t]; }
    }
    __syncthreads();
    for (int e = t; e < nb; e += 256) {
        unsigned int w = mypk[e];
        int p = atomicAdd(&base[w >> 20], 1);
        ssrc[bs + p] = (int)(w & 0xFFFFFu);
    }
}

// ---------------- Gather layer 1 (2 heads x 32 ch) ----------------
__global__ void k_gather1(const int* __restrict__ rs, const int* __restrict__ cur,
                          const int* __restrict__ ssrc, const float* __restrict__ h1,
                          const float* __restrict__ als1, const float* __restrict__ ald1,
                          const float* __restrict__ b1, float* __restrict__ h2, int N)
{
    int node = blockIdx.x * 4 + (threadIdx.x >> 6);
    if (node >= N) return;
    int c = threadIdx.x & 63;
    int head = c >> 5;
    float ad = ald1[node * 2 + head];

    int beg = rs[node], end = cur[node];
    float acc = 0.f, wsum = 0.f;
    int i = beg;
    for (; i + 1 < end; i += 2) {
        int s0 = ssrc[i], s1 = ssrc[i + 1];
        float l0 = als1[s0 * 2 + head] + ad;
        float l1 = als1[s1 * 2 + head] + ad;
        float hv0 = h1[s0 * 64 + c];
        float hv1 = h1[s1 * 64 + c];
        l0 = (l0 >= 0.f) ? l0 : NEG_SLOPE * l0;
        l1 = (l1 >= 0.f) ? l1 : NEG_SLOPE * l1;
        float w0 = __expf(l0), w1 = __expf(l1);
        acc += w0 * hv0; wsum += w0;
        acc += w1 * hv1; wsum += w1;
    }
    if (i < end) {
        int s0 = ssrc[i];
        float l0 = als1[s0 * 2 + head] + ad;
        float hv0 = h1[s0 * 64 + c];
        l0 = (l0 >= 0.f) ? l0 : NEG_SLOPE * l0;
        float w0 = __expf(l0);
        acc += w0 * hv0; wsum += w0;
    }
    float v = acc / (wsum + 1e-16f) + b1[c];
    h2[(size_t)node * 64 + c] = fmaxf(v, 0.f);
}

// ---------------- Node kernel 2: h3 = h2 @ W2, layer-2 logits ----------------
__global__ void k_node2(const float* __restrict__ h2, const float* __restrict__ W2,
                        const float* __restrict__ a_src2, const float* __restrict__ a_dst2,
                        float* __restrict__ h3, float* __restrict__ als2, float* __restrict__ ald2,
                        int N)
{
    __shared__ float sh[4][64];
    int g = threadIdx.x >> 6;
    int node = blockIdx.x * 4 + g;
    int j = threadIdx.x & 63;

    float hv = (node < N) ? h2[(size_t)node * 64 + j] : 0.f;
    sh[g][j] = hv;
    __syncthreads();
    if (node >= N) return;

    float acc = 0.f;
#pragma unroll
    for (int k = 0; k < 64; k++) acc += sh[g][k] * W2[k * 64 + j];
    h3[(size_t)node * 64 + j] = acc;

    float ps = acc * a_src2[j];
    float pd = acc * a_dst2[j];
#pragma unroll
    for (int m = 32; m >= 1; m >>= 1) { ps += __shfl_xor(ps, m); pd += __shfl_xor(pd, m); }
    if (j == 0) { als2[node] = ps; ald2[node] = pd; }
}

// ---------------- Gather layer 2 (1 head, 64 ch) + LayerNorm ----------------
__global__ void k_gather2(const int* __restrict__ rs, const int* __restrict__ cur,
                          const int* __restrict__ ssrc, const float* __restrict__ h3,
                          const float* __restrict__ als2, const float* __restrict__ ald2,
                          const float* __restrict__ b2, const float* __restrict__ gamma,
                          const float* __restrict__ beta, float* __restrict__ out, int N)
{
    int node = blockIdx.x * 4 + (threadIdx.x >> 6);
    if (node >= N) return;
    int c = threadIdx.x & 63;
    float ad = ald2[node];

    int beg = rs[node], end = cur[node];
    float acc = 0.f, wsum = 0.f;
    int i = beg;
    for (; i + 1 < end; i += 2) {
        int s0 = ssrc[i], s1 = ssrc[i + 1];
        float l0 = als2[s0] + ad;
        float l1 = als2[s1] + ad;
        float hv0 = h3[s0 * 64 + c];
        float hv1 = h3[s1 * 64 + c];
        l0 = (l0 >= 0.f) ? l0 : NEG_SLOPE * l0;
        l1 = (l1 >= 0.f) ? l1 : NEG_SLOPE * l1;
        float w0 = __expf(l0), w1 = __expf(l1);
        acc += w0 * hv0; wsum += w0;
        acc += w1 * hv1; wsum += w1;
    }
    if (i < end) {
        int s0 = ssrc[i];
        float l0 = als2[s0] + ad;
        float hv0 = h3[s0 * 64 + c];
        l0 = (l0 >= 0.f) ? l0 : NEG_SLOPE * l0;
        float w0 = __expf(l0);
        acc += w0 * hv0; wsum += w0;
    }
    float o = acc / (wsum + 1e-16f) + b2[c];

    float s = o;
#pragma unroll
    for (int m = 32; m >= 1; m >>= 1) s += __shfl_xor(s, m);
    float mu = s * (1.f / 64.f);
    float dv = o - mu;
    float v = dv * dv;
#pragma unroll
    for (int m = 32; m >= 1; m >>= 1) v += __shfl_xor(v, m);
    v *= (1.f / 64.f);
    out[(size_t)node * 64 + c] = dv * rsqrtf(v + 1e-5f) * gamma[c] + beta[c];
}

extern "C" void kernel_launch(void* const* d_in, const int* in_sizes, int n_in,
                              void* d_out, int out_size, void* d_ws, size_t ws_size,
                              hipStream_t stream) {
    const float* x        = (const float*)d_in[0];
    const int*   ei       = (const int*)  d_in[1];
    const int*   type_ids = (const int*)  d_in[2];
    const float* type_emb = (const float*)d_in[3];
    const float* W1       = (const float*)d_in[4];
    const float* a_src1   = (const float*)d_in[5];
    const float* a_dst1   = (const float*)d_in[6];
    const float* b1       = (const float*)d_in[7];
    const float* W2       = (const float*)d_in[8];
    const float* a_src2   = (const float*)d_in[9];
    const float* a_dst2   = (const float*)d_in[10];
    const float* b2       = (const float*)d_in[11];
    const float* gamma    = (const float*)d_in[12];
    const float* beta     = (const float*)d_in[13];

    int N = in_sizes[0] / 5;
    int E = in_sizes[1] / 2;
    int EV = E + N;
    int NBKT = (N + BKT_NODES - 1) >> BKT_SHIFT;

    // Workspace layout
    float* bufA = (float*)d_ws;               // h1, then h3   [N*64]
    float* bufB = bufA + (size_t)N * 64;      // pk (phase A/B), then h2 [N*64]
    float* als1 = bufB + (size_t)N * 64;      // [2N]
    float* ald1 = als1 + (size_t)N * 2;       // [2N]
    float* als2 = ald1 + (size_t)N * 2;       // [N]
    float* ald2 = als2 + (size_t)N;           // [N]
    int*   rs   = (int*)(ald2 + (size_t)N);   // [N]
    int*   cur  = rs + N;                     // [N]
    int*   bcnt = cur + N;                    // [1024]
    int*   bst  = bcnt + 1024;                // [1024]
    int*   ssrc = bst + 1024;                 // [EV]
    unsigned int* pk = (unsigned int*)bufB;   // NBKT*BKT_CAP uints <= N*64 floats

    dim3 tb(256);
    dim3 nb((N + 3) / 4);

    // Node features + layer-1 logits
    k_node1<<<nb, tb, 0, stream>>>(x, type_ids, type_emb, W1, a_src1, a_dst1,
                                   bufA, als1, ald1, N);

    // CSR build (dst-sorted) via 128-node buckets
    hipMemsetAsync(bcnt, 0, NBKT * sizeof(int), stream);
    k_bucket<<<dim3((EV + 255) / 256), tb, 0, stream>>>(ei, pk, bcnt, E, N);
    k_bscan<<<dim3(1), dim3(1024), 0, stream>>>(bcnt, bst, NBKT);
    k_build<<<dim3(NBKT), tb, 0, stream>>>(pk, bcnt, bst, rs, cur, ssrc, N);

    // Layer 1 aggregate -> h2 (overwrites pk region, already consumed)
    k_gather1<<<nb, tb, 0, stream>>>(rs, cur, ssrc, bufA, als1, ald1, b1, bufB, N);
    // Projection + layer-2 logits
    k_node2<<<nb, tb, 0, stream>>>(bufB, W2, a_src2, a_dst2, bufA, als2, ald2, N);
    // Layer 2 aggregate + LayerNorm -> out
    k_gather2<<<nb, tb, 0, stream>>>(rs, cur, ssrc, bufA, als2, ald2, b2, gamma, beta,
                                     (float*)d_out, N);
}

// Round 4
// 636.786 us; speedup vs baseline: 2.2043x; 2.2043x over previous
//
#include <hip/hip_runtime.h>

#define NEG_SLOPE 0.2f
#define BKT_SHIFT 8
#define BKT_NODES 256
#define BKT_CAP 10240
#define SRC_SHIFT 18
#define SRC_MASK 0x3FFFF
#define CHUNK 4096
#define NBMAX 512

// ---------------- Kernel: node prep layer 1 ----------------
__global__ void k_node1(const float* __restrict__ x, const int* __restrict__ type_ids,
                        const float* __restrict__ type_emb, const float* __restrict__ W1,
                        const float* __restrict__ a_src1, const float* __restrict__ a_dst1,
                        float* __restrict__ h1, float* __restrict__ als1, float* __restrict__ ald1,
                        int N)
{
    int node = blockIdx.x * 4 + (threadIdx.x >> 6);
    int j = threadIdx.x & 63;
    if (node >= N) return;

    float xin[21];
#pragma unroll
    for (int k = 0; k < 5; k++) xin[k] = x[node * 5 + k];
    int t = type_ids[node];
#pragma unroll
    for (int k = 0; k < 16; k++) xin[5 + k] = type_emb[t * 16 + k];

    float h = 0.f;
#pragma unroll
    for (int k = 0; k < 21; k++) h += xin[k] * W1[k * 64 + j];
    h1[node * 64 + j] = h;

    int head = j >> 5, lane = j & 31;
    float ps = h * a_src1[head * 32 + lane];
    float pd = h * a_dst1[head * 32 + lane];
#pragma unroll
    for (int m = 16; m >= 1; m >>= 1) { ps += __shfl_xor(ps, m); pd += __shfl_xor(pd, m); }
    if (lane == 0) { als1[node * 2 + head] = ps; ald1[node * 2 + head] = pd; }
}

// ---------------- CSR build, phase A: LDS-staged bucket append ----------------
// Block bins CHUNK edges into NBKT buckets in LDS, reserves global space with one
// atomic per (block,bucket), flushes bucket-contiguous runs coalesced.
__global__ void k_bucketA(const int* __restrict__ ei, unsigned int* __restrict__ pk,
                          int* __restrict__ bcnt, int E, int EV, int NBKT)
{
    __shared__ unsigned int stage[CHUNK];
    __shared__ unsigned short stageB[CHUNK];
    __shared__ int cnt[NBMAX];    // counts -> inclusive scan
    __shared__ int excl[NBMAX];   // exclusive offsets
    __shared__ int curp[NBMAX];   // scatter cursors (temp: orig counts)
    __shared__ int gbase[NBMAX];  // reserved global base

    int t = threadIdx.x;
    int e0 = blockIdx.x * CHUNK;

    for (int i = t; i < NBMAX; i += 256) cnt[i] = 0;
    __syncthreads();

    // pass 1: count
    for (int i = t; i < CHUNK; i += 256) {
        int e = e0 + i;
        if (e >= EV) break;
        int d = (e < E) ? ei[E + e] : (e - E);
        atomicAdd(&cnt[d >> BKT_SHIFT], 1);
    }
    __syncthreads();
    for (int i = t; i < NBMAX; i += 256) curp[i] = cnt[i];  // save orig counts
    __syncthreads();
    // inclusive scan of cnt[0..512), 2 elems/thread Hillis-Steele
    for (int off = 1; off < NBMAX; off <<= 1) {
        int v0 = (t >= off) ? cnt[t - off] : 0;
        int v1 = (t + 256 >= off) ? cnt[t + 256 - off] : 0;
        __syncthreads();
        cnt[t] += v0; cnt[t + 256] += v1;
        __syncthreads();
    }
    for (int i = t; i < NBMAX; i += 256) {
        int o = curp[i];
        int ex = cnt[i] - o;
        excl[i] = ex;
        curp[i] = ex;
    }
    __syncthreads();
    // reserve global space (one atomic per non-empty bucket)
    for (int b = t; b < NBKT; b += 256) {
        int c = cnt[b] - excl[b];
        gbase[b] = (c > 0) ? atomicAdd(&bcnt[b], c) : 0;
    }
    __syncthreads();
    // pass 2: LDS scatter (bucket-ordered)
    for (int i = t; i < CHUNK; i += 256) {
        int e = e0 + i;
        if (e >= EV) break;
        int s, d;
        if (e < E) { s = ei[e]; d = ei[E + e]; } else { s = d = e - E; }
        int b = d >> BKT_SHIFT;
        int p = atomicAdd(&curp[b], 1);
        stage[p] = (unsigned)s | ((unsigned)(d & (BKT_NODES - 1)) << SRC_SHIFT);
        stageB[p] = (unsigned short)b;
    }
    __syncthreads();
    // flush: coalesced, runs contiguous per bucket
    int total = EV - e0; if (total > CHUNK) total = CHUNK;
    for (int i = t; i < total; i += 256) {
        int b = stageB[i];
        int idx = gbase[b] + (i - excl[b]);
        if (idx < BKT_CAP) pk[(size_t)b * BKT_CAP + idx] = stage[i];
    }
}

// ---------------- CSR build: bucket-start scan (NBKT <= 1024) ----------------
__global__ void k_bscan(const int* __restrict__ bcnt, int* __restrict__ bstart, int NBKT)
{
    __shared__ int sh[1024];
    int t = threadIdx.x;
    int v = (t < NBKT) ? min(bcnt[t], BKT_CAP) : 0;
    sh[t] = v;
    __syncthreads();
    for (int off = 1; off < 1024; off <<= 1) {
        int xv = (t >= off) ? sh[t - off] : 0;
        __syncthreads();
        sh[t] += xv;
        __syncthreads();
    }
    if (t < NBKT) bstart[t] = sh[t] - v;
}

// ---------------- CSR build, phase B: per-bucket counting sort ----------------
__global__ void k_build(const unsigned int* __restrict__ pk, const int* __restrict__ bcnt,
                        const int* __restrict__ bstart, int* __restrict__ rs,
                        int* __restrict__ cur, int* __restrict__ ssrc, int N)
{
    __shared__ int cnt[BKT_NODES];   // counts -> inclusive scan
    __shared__ int cursor[BKT_NODES];
    __shared__ int orig[BKT_NODES];
    int b = blockIdx.x;
    int t = threadIdx.x;
    int nb = min(bcnt[b], BKT_CAP);
    int bs = bstart[b];
    cnt[t] = 0;
    __syncthreads();
    const unsigned int* mypk = pk + (size_t)b * BKT_CAP;
    for (int e = t; e < nb; e += 256)
        atomicAdd(&cnt[mypk[e] >> SRC_SHIFT], 1);
    __syncthreads();
    orig[t] = cnt[t];
    __syncthreads();
    for (int off = 1; off < BKT_NODES; off <<= 1) {
        int v = (t >= off) ? cnt[t - off] : 0;
        __syncthreads();
        cnt[t] += v;
        __syncthreads();
    }
    {
        int c = orig[t];
        int ex = cnt[t] - c;
        cursor[t] = ex;
        int node = (b << BKT_SHIFT) + t;
        if (node < N) { rs[node] = bs + ex; cur[node] = bs + ex + c; }
    }
    __syncthreads();
    for (int e = t; e < nb; e += 256) {
        unsigned int w = mypk[e];
        int p = atomicAdd(&cursor[w >> SRC_SHIFT], 1);
        ssrc[bs + p] = (int)(w & SRC_MASK);
    }
}

// ---------------- Gather layer 1 (2 heads x 32 ch) ----------------
__global__ void k_gather1(const int* __restrict__ rs, const int* __restrict__ cur,
                          const int* __restrict__ ssrc, const float* __restrict__ h1,
                          const float* __restrict__ als1, const float* __restrict__ ald1,
                          const float* __restrict__ b1, float* __restrict__ h2, int N)
{
    int node = blockIdx.x * 4 + (threadIdx.x >> 6);
    if (node >= N) return;
    int c = threadIdx.x & 63;
    int head = c >> 5;
    float ad = ald1[node * 2 + head];

    int beg = rs[node], end = cur[node];
    float acc = 0.f, wsum = 0.f;
    int i = beg;
    for (; i + 1 < end; i += 2) {
        int s0 = ssrc[i], s1 = ssrc[i + 1];
        float l0 = als1[s0 * 2 + head] + ad;
        float l1 = als1[s1 * 2 + head] + ad;
        float hv0 = h1[s0 * 64 + c];
        float hv1 = h1[s1 * 64 + c];
        l0 = (l0 >= 0.f) ? l0 : NEG_SLOPE * l0;
        l1 = (l1 >= 0.f) ? l1 : NEG_SLOPE * l1;
        float w0 = __expf(l0), w1 = __expf(l1);
        acc += w0 * hv0; wsum += w0;
        acc += w1 * hv1; wsum += w1;
    }
    if (i < end) {
        int s0 = ssrc[i];
        float l0 = als1[s0 * 2 + head] + ad;
        float hv0 = h1[s0 * 64 + c];
        l0 = (l0 >= 0.f) ? l0 : NEG_SLOPE * l0;
        float w0 = __expf(l0);
        acc += w0 * hv0; wsum += w0;
    }
    float v = acc / (wsum + 1e-16f) + b1[c];
    h2[(size_t)node * 64 + c] = fmaxf(v, 0.f);
}

// ---------------- Node kernel 2: h3 = h2 @ W2, layer-2 logits ----------------
__global__ void k_node2(const float* __restrict__ h2, const float* __restrict__ W2,
                        const float* __restrict__ a_src2, const float* __restrict__ a_dst2,
                        float* __restrict__ h3, float* __restrict__ als2, float* __restrict__ ald2,
                        int N)
{
    __shared__ float sh[4][64];
    int g = threadIdx.x >> 6;
    int node = blockIdx.x * 4 + g;
    int j = threadIdx.x & 63;

    float hv = (node < N) ? h2[(size_t)node * 64 + j] : 0.f;
    sh[g][j] = hv;
    __syncthreads();
    if (node >= N) return;

    float acc = 0.f;
#pragma unroll
    for (int k = 0; k < 64; k++) acc += sh[g][k] * W2[k * 64 + j];
    h3[(size_t)node * 64 + j] = acc;

    float ps = acc * a_src2[j];
    float pd = acc * a_dst2[j];
#pragma unroll
    for (int m = 32; m >= 1; m >>= 1) { ps += __shfl_xor(ps, m); pd += __shfl_xor(pd, m); }
    if (j == 0) { als2[node] = ps; ald2[node] = pd; }
}

// ---------------- Gather layer 2 (1 head, 64 ch) + LayerNorm ----------------
__global__ void k_gather2(const int* __restrict__ rs, const int* __restrict__ cur,
                          const int* __restrict__ ssrc, const float* __restrict__ h3,
                          const float* __restrict__ als2, const float* __restrict__ ald2,
                          const float* __restrict__ b2, const float* __restrict__ gamma,
                          const float* __restrict__ beta, float* __restrict__ out, int N)
{
    int node = blockIdx.x * 4 + (threadIdx.x >> 6);
    if (node >= N) return;
    int c = threadIdx.x & 63;
    float ad = ald2[node];

    int beg = rs[node], end = cur[node];
    float acc = 0.f, wsum = 0.f;
    int i = beg;
    for (; i + 1 < end; i += 2) {
        int s0 = ssrc[i], s1 = ssrc[i + 1];
        float l0 = als2[s0] + ad;
        float l1 = als2[s1] + ad;
        float hv0 = h3[s0 * 64 + c];
        float hv1 = h3[s1 * 64 + c];
        l0 = (l0 >= 0.f) ? l0 : NEG_SLOPE * l0;
        l1 = (l1 >= 0.f) ? l1 : NEG_SLOPE * l1;
        float w0 = __expf(l0), w1 = __expf(l1);
        acc += w0 * hv0; wsum += w0;
        acc += w1 * hv1; wsum += w1;
    }
    if (i < end) {
        int s0 = ssrc[i];
        float l0 = als2[s0] + ad;
        float hv0 = h3[s0 * 64 + c];
        l0 = (l0 >= 0.f) ? l0 : NEG_SLOPE * l0;
        float w0 = __expf(l0);
        acc += w0 * hv0; wsum += w0;
    }
    float o = acc / (wsum + 1e-16f) + b2[c];

    float s = o;
#pragma unroll
    for (int m = 32; m >= 1; m >>= 1) s += __shfl_xor(s, m);
    float mu = s * (1.f / 64.f);
    float dv = o - mu;
    float v = dv * dv;
#pragma unroll
    for (int m = 32; m >= 1; m >>= 1) v += __shfl_xor(v, m);
    v *= (1.f / 64.f);
    out[(size_t)node * 64 + c] = dv * rsqrtf(v + 1e-5f) * gamma[c] + beta[c];
}

extern "C" void kernel_launch(void* const* d_in, const int* in_sizes, int n_in,
                              void* d_out, int out_size, void* d_ws, size_t ws_size,
                              hipStream_t stream) {
    const float* x        = (const float*)d_in[0];
    const int*   ei       = (const int*)  d_in[1];
    const int*   type_ids = (const int*)  d_in[2];
    const float* type_emb = (const float*)d_in[3];
    const float* W1       = (const float*)d_in[4];
    const float* a_src1   = (const float*)d_in[5];
    const float* a_dst1   = (const float*)d_in[6];
    const float* b1       = (const float*)d_in[7];
    const float* W2       = (const float*)d_in[8];
    const float* a_src2   = (const float*)d_in[9];
    const float* a_dst2   = (const float*)d_in[10];
    const float* b2       = (const float*)d_in[11];
    const float* gamma    = (const float*)d_in[12];
    const float* beta     = (const float*)d_in[13];

    int N = in_sizes[0] / 5;
    int E = in_sizes[1] / 2;
    int EV = E + N;
    int NBKT = (N + BKT_NODES - 1) >> BKT_SHIFT;

    // Workspace layout
    float* bufA = (float*)d_ws;               // h1, then h3   [N*64]
    float* bufB = bufA + (size_t)N * 64;      // pk (build), then h2 [N*64]
    float* als1 = bufB + (size_t)N * 64;      // [2N]
    float* ald1 = als1 + (size_t)N * 2;       // [2N]
    float* als2 = ald1 + (size_t)N * 2;       // [N]
    float* ald2 = als2 + (size_t)N;           // [N]
    int*   rs   = (int*)(ald2 + (size_t)N);   // [N]
    int*   cur  = rs + N;                     // [N]
    int*   bcnt = cur + N;                    // [1024]
    int*   bst  = bcnt + 1024;                // [1024]
    int*   ssrc = bst + 1024;                 // [EV]
    unsigned int* pk = (unsigned int*)bufB;   // NBKT*BKT_CAP uints (16 MB) <= N*64 floats

    dim3 tb(256);
    dim3 nb((N + 3) / 4);

    // Node features + layer-1 logits
    k_node1<<<nb, tb, 0, stream>>>(x, type_ids, type_emb, W1, a_src1, a_dst1,
                                   bufA, als1, ald1, N);

    // CSR build (dst-sorted) via LDS-staged 256-node buckets
    hipMemsetAsync(bcnt, 0, NBKT * sizeof(int), stream);
    k_bucketA<<<dim3((EV + CHUNK - 1) / CHUNK), tb, 0, stream>>>(ei, pk, bcnt, E, EV, NBKT);
    k_bscan<<<dim3(1), dim3(1024), 0, stream>>>(bcnt, bst, NBKT);
    k_build<<<dim3(NBKT), tb, 0, stream>>>(pk, bcnt, bst, rs, cur, ssrc, N);

    // Layer 1 aggregate -> h2 (overwrites pk region, already consumed)
    k_gather1<<<nb, tb, 0, stream>>>(rs, cur, ssrc, bufA, als1, ald1, b1, bufB, N);
    // Projection + layer-2 logits
    k_node2<<<nb, tb, 0, stream>>>(bufB, W2, a_src2, a_dst2, bufA, als2, ald2, N);
    // Layer 2 aggregate + LayerNorm -> out
    k_gather2<<<nb, tb, 0, stream>>>(rs, cur, ssrc, bufA, als2, ald2, b2, gamma, beta,
                                     (float*)d_out, N);
}

// Round 5
// 513.235 us; speedup vs baseline: 2.7350x; 1.2407x over previous
//
#include <hip/hip_runtime.h>
#include <hip/hip_fp16.h>

#define NEG_SLOPE 0.2f
#define BKT_SHIFT 8
#define BKT_NODES 256
#define BKT_CAP 10240
#define SRC_SHIFT 18
#define SRC_MASK 0x3FFFF
#define CHUNK 4096
#define NBMAX 512

// ---------------- Kernel: node prep layer 1 ----------------
// h1 (fp16) + layer-1 attention logits.
__global__ void k_node1(const float* __restrict__ x, const int* __restrict__ type_ids,
                        const float* __restrict__ type_emb, const float* __restrict__ W1,
                        const float* __restrict__ a_src1, const float* __restrict__ a_dst1,
                        __half2* __restrict__ h1h, float* __restrict__ als1, float* __restrict__ ald1,
                        int N)
{
    int node = blockIdx.x * 4 + (threadIdx.x >> 6);
    int j = threadIdx.x & 63;
    if (node >= N) return;

    float xin[21];
#pragma unroll
    for (int k = 0; k < 5; k++) xin[k] = x[node * 5 + k];
    int t = type_ids[node];
#pragma unroll
    for (int k = 0; k < 16; k++) xin[5 + k] = type_emb[t * 16 + k];

    float h = 0.f;
#pragma unroll
    for (int k = 0; k < 21; k++) h += xin[k] * W1[k * 64 + j];

    float hn = __shfl_xor(h, 1);
    if ((j & 1) == 0)
        h1h[node * 32 + (j >> 1)] = __floats2half2_rn(h, hn);

    int head = j >> 5, lane = j & 31;
    float ps = h * a_src1[head * 32 + lane];
    float pd = h * a_dst1[head * 32 + lane];
#pragma unroll
    for (int m = 16; m >= 1; m >>= 1) { ps += __shfl_xor(ps, m); pd += __shfl_xor(pd, m); }
    if (lane == 0) { als1[node * 2 + head] = ps; ald1[node * 2 + head] = pd; }
}

// ---------------- CSR build, phase A: LDS-staged bucket append ----------------
__global__ void k_bucketA(const int* __restrict__ ei, unsigned int* __restrict__ pk,
                          int* __restrict__ bcnt, int E, int EV, int NBKT)
{
    __shared__ unsigned int stage[CHUNK];
    __shared__ unsigned short stageB[CHUNK];
    __shared__ int cnt[NBMAX];
    __shared__ int excl[NBMAX];
    __shared__ int curp[NBMAX];
    __shared__ int gbase[NBMAX];

    int t = threadIdx.x;
    int e0 = blockIdx.x * CHUNK;

    for (int i = t; i < NBMAX; i += 256) cnt[i] = 0;
    __syncthreads();

    for (int i = t; i < CHUNK; i += 256) {
        int e = e0 + i;
        if (e >= EV) break;
        int d = (e < E) ? ei[E + e] : (e - E);
        atomicAdd(&cnt[d >> BKT_SHIFT], 1);
    }
    __syncthreads();
    for (int i = t; i < NBMAX; i += 256) curp[i] = cnt[i];
    __syncthreads();
    for (int off = 1; off < NBMAX; off <<= 1) {
        int v0 = (t >= off) ? cnt[t - off] : 0;
        int v1 = (t + 256 >= off) ? cnt[t + 256 - off] : 0;
        __syncthreads();
        cnt[t] += v0; cnt[t + 256] += v1;
        __syncthreads();
    }
    for (int i = t; i < NBMAX; i += 256) {
        int o = curp[i];
        int ex = cnt[i] - o;
        excl[i] = ex;
        curp[i] = ex;
    }
    __syncthreads();
    for (int b = t; b < NBKT; b += 256) {
        int c = cnt[b] - excl[b];
        gbase[b] = (c > 0) ? atomicAdd(&bcnt[b], c) : 0;
    }
    __syncthreads();
    for (int i = t; i < CHUNK; i += 256) {
        int e = e0 + i;
        if (e >= EV) break;
        int s, d;
        if (e < E) { s = ei[e]; d = ei[E + e]; } else { s = d = e - E; }
        int b = d >> BKT_SHIFT;
        int p = atomicAdd(&curp[b], 1);
        stage[p] = (unsigned)s | ((unsigned)(d & (BKT_NODES - 1)) << SRC_SHIFT);
        stageB[p] = (unsigned short)b;
    }
    __syncthreads();
    int total = EV - e0; if (total > CHUNK) total = CHUNK;
    for (int i = t; i < total; i += 256) {
        int b = stageB[i];
        int idx = gbase[b] + (i - excl[b]);
        if (idx < BKT_CAP) pk[(size_t)b * BKT_CAP + idx] = stage[i];
    }
}

// ---------------- CSR build: bucket-start scan ----------------
__global__ void k_bscan(const int* __restrict__ bcnt, int* __restrict__ bstart, int NBKT)
{
    __shared__ int sh[1024];
    int t = threadIdx.x;
    int v = (t < NBKT) ? min(bcnt[t], BKT_CAP) : 0;
    sh[t] = v;
    __syncthreads();
    for (int off = 1; off < 1024; off <<= 1) {
        int xv = (t >= off) ? sh[t - off] : 0;
        __syncthreads();
        sh[t] += xv;
        __syncthreads();
    }
    if (t < NBKT) bstart[t] = sh[t] - v;
}

// ---------------- CSR build, phase B: per-bucket counting sort ----------------
__global__ void k_build(const unsigned int* __restrict__ pk, const int* __restrict__ bcnt,
                        const int* __restrict__ bstart, int* __restrict__ rs,
                        int* __restrict__ cur, int* __restrict__ ssrc, int N)
{
    __shared__ int cnt[BKT_NODES];
    __shared__ int cursor[BKT_NODES];
    __shared__ int orig[BKT_NODES];
    int b = blockIdx.x;
    int t = threadIdx.x;
    int nb = min(bcnt[b], BKT_CAP);
    int bs = bstart[b];
    cnt[t] = 0;
    __syncthreads();
    const unsigned int* mypk = pk + (size_t)b * BKT_CAP;
    for (int e = t; e < nb; e += 256)
        atomicAdd(&cnt[mypk[e] >> SRC_SHIFT], 1);
    __syncthreads();
    orig[t] = cnt[t];
    __syncthreads();
    for (int off = 1; off < BKT_NODES; off <<= 1) {
        int v = (t >= off) ? cnt[t - off] : 0;
        __syncthreads();
        cnt[t] += v;
        __syncthreads();
    }
    {
        int c = orig[t];
        int ex = cnt[t] - c;
        cursor[t] = ex;
        int node = (b << BKT_SHIFT) + t;
        if (node < N) { rs[node] = bs + ex; cur[node] = bs + ex + c; }
    }
    __syncthreads();
    for (int e = t; e < nb; e += 256) {
        unsigned int w = mypk[e];
        int p = atomicAdd(&cursor[w >> SRC_SHIFT], 1);
        ssrc[bs + p] = (int)(w & SRC_MASK);
    }
}

// ---------------- Fused gather layer 1 + W2 projection + layer-2 logits ----------------
// One wave per node. Lanes 0-31 process even edges, 32-63 odd edges; each lane
// owns channel pair (2*sub, 2*sub+1). After shfl-combine, h2 lives across the
// wave; W2 matmul splits k-range by half and recombines. Emits fp16 h3 + logits.
__global__ void k_gather1(const int* __restrict__ rs, const int* __restrict__ cur,
                          const int* __restrict__ ssrc, const __half2* __restrict__ h1h,
                          const float* __restrict__ als1, const float* __restrict__ ald1,
                          const float* __restrict__ b1, const float* __restrict__ W2,
                          const float* __restrict__ a_src2, const float* __restrict__ a_dst2,
                          __half2* __restrict__ h3h, float* __restrict__ als2,
                          float* __restrict__ ald2, int N)
{
    __shared__ float sh[4][64];
    int wv = threadIdx.x >> 6;
    int node = blockIdx.x * 4 + wv;
    if (node >= N) return;
    int l = threadIdx.x & 63;
    int par = l >> 5;         // edge parity this lane handles
    int sub = l & 31;         // channel-pair index
    int head = sub >> 4;      // channels 2sub,2sub+1 share a head
    float ad = ald1[node * 2 + head];

    int beg = rs[node], end = cur[node];
    float a0 = 0.f, a1 = 0.f, wsum = 0.f;
    int i = beg + par;
    for (; i + 2 < end; i += 4) {
        int s0 = ssrc[i], s1 = ssrc[i + 2];
        float l0 = als1[s0 * 2 + head] + ad;
        float l1 = als1[s1 * 2 + head] + ad;
        __half2 hv0 = h1h[s0 * 32 + sub];
        __half2 hv1 = h1h[s1 * 32 + sub];
        l0 = (l0 >= 0.f) ? l0 : NEG_SLOPE * l0;
        l1 = (l1 >= 0.f) ? l1 : NEG_SLOPE * l1;
        float w0 = __expf(l0), w1 = __expf(l1);
        float2 f0 = __half22float2(hv0), f1 = __half22float2(hv1);
        a0 += w0 * f0.x; a1 += w0 * f0.y; wsum += w0;
        a0 += w1 * f1.x; a1 += w1 * f1.y; wsum += w1;
    }
    for (; i < end; i += 2) {
        int s0 = ssrc[i];
        float l0 = als1[s0 * 2 + head] + ad;
        __half2 hv0 = h1h[s0 * 32 + sub];
        l0 = (l0 >= 0.f) ? l0 : NEG_SLOPE * l0;
        float w0 = __expf(l0);
        float2 f0 = __half22float2(hv0);
        a0 += w0 * f0.x; a1 += w0 * f0.y; wsum += w0;
    }
    a0 += __shfl_xor(a0, 32);
    a1 += __shfl_xor(a1, 32);
    wsum += __shfl_xor(wsum, 32);
    float inv = 1.f / (wsum + 1e-16f);
    int c0 = 2 * sub, c1 = c0 + 1;
    float v0 = fmaxf(a0 * inv + b1[c0], 0.f);
    float v1 = fmaxf(a1 * inv + b1[c1], 0.f);

    // stash h2 in this wave's LDS slot (same-wave RAW, no barrier needed)
    if (par == 0) { sh[wv][c0] = v0; sh[wv][c1] = v1; }

    // W2 matmul: this lane computes out channels c0,c1 over k in [par*32, par*32+32)
    float h30 = 0.f, h31 = 0.f;
    int k0 = par * 32;
#pragma unroll
    for (int k = 0; k < 32; k++) {
        float hk = sh[wv][k0 + k];
        float2 w2 = *((const float2*)(W2 + (k0 + k) * 64) + sub);
        h30 += hk * w2.x; h31 += hk * w2.y;
    }
    h30 += __shfl_xor(h30, 32);
    h31 += __shfl_xor(h31, 32);

    if (par == 0)
        h3h[node * 32 + sub] = __floats2half2_rn(h30, h31);

    float ps = h30 * a_src2[c0] + h31 * a_src2[c1];
    float pd = h30 * a_dst2[c0] + h31 * a_dst2[c1];
#pragma unroll
    for (int m = 16; m >= 1; m >>= 1) { ps += __shfl_xor(ps, m); pd += __shfl_xor(pd, m); }
    if (l == 0) { als2[node] = ps; ald2[node] = pd; }
}

// ---------------- Gather layer 2 + LayerNorm ----------------
__global__ void k_gather2(const int* __restrict__ rs, const int* __restrict__ cur,
                          const int* __restrict__ ssrc, const __half2* __restrict__ h3h,
                          const float* __restrict__ als2, const float* __restrict__ ald2,
                          const float* __restrict__ b2, const float* __restrict__ gamma,
                          const float* __restrict__ beta, float* __restrict__ out, int N)
{
    int node = blockIdx.x * 4 + (threadIdx.x >> 6);
    if (node >= N) return;
    int l = threadIdx.x & 63;
    int par = l >> 5;
    int sub = l & 31;
    float ad = ald2[node];

    int beg = rs[node], end = cur[node];
    float a0 = 0.f, a1 = 0.f, wsum = 0.f;
    int i = beg + par;
    for (; i + 2 < end; i += 4) {
        int s0 = ssrc[i], s1 = ssrc[i + 2];
        float l0 = als2[s0] + ad;
        float l1 = als2[s1] + ad;
        __half2 hv0 = h3h[s0 * 32 + sub];
        __half2 hv1 = h3h[s1 * 32 + sub];
        l0 = (l0 >= 0.f) ? l0 : NEG_SLOPE * l0;
        l1 = (l1 >= 0.f) ? l1 : NEG_SLOPE * l1;
        float w0 = __expf(l0), w1 = __expf(l1);
        float2 f0 = __half22float2(hv0), f1 = __half22float2(hv1);
        a0 += w0 * f0.x; a1 += w0 * f0.y; wsum += w0;
        a0 += w1 * f1.x; a1 += w1 * f1.y; wsum += w1;
    }
    for (; i < end; i += 2) {
        int s0 = ssrc[i];
        float l0 = als2[s0] + ad;
        __half2 hv0 = h3h[s0 * 32 + sub];
        l0 = (l0 >= 0.f) ? l0 : NEG_SLOPE * l0;
        float w0 = __expf(l0);
        float2 f0 = __half22float2(hv0);
        a0 += w0 * f0.x; a1 += w0 * f0.y; wsum += w0;
    }
    a0 += __shfl_xor(a0, 32);
    a1 += __shfl_xor(a1, 32);
    wsum += __shfl_xor(wsum, 32);
    float inv = 1.f / (wsum + 1e-16f);
    int c0 = 2 * sub, c1 = c0 + 1;
    float o0 = a0 * inv + b2[c0];
    float o1 = a1 * inv + b2[c1];

    float s = o0 + o1;
#pragma unroll
    for (int m = 16; m >= 1; m >>= 1) s += __shfl_xor(s, m);
    float mu = s * (1.f / 64.f);
    float d0 = o0 - mu, d1 = o1 - mu;
    float v = d0 * d0 + d1 * d1;
#pragma unroll
    for (int m = 16; m >= 1; m >>= 1) v += __shfl_xor(v, m);
    v *= (1.f / 64.f);
    float r = rsqrtf(v + 1e-5f);
    if (par == 0) {
        float2 res;
        res.x = d0 * r * gamma[c0] + beta[c0];
        res.y = d1 * r * gamma[c1] + beta[c1];
        ((float2*)out)[(size_t)node * 32 + sub] = res;
    }
}

extern "C" void kernel_launch(void* const* d_in, const int* in_sizes, int n_in,
                              void* d_out, int out_size, void* d_ws, size_t ws_size,
                              hipStream_t stream) {
    const float* x        = (const float*)d_in[0];
    const int*   ei       = (const int*)  d_in[1];
    const int*   type_ids = (const int*)  d_in[2];
    const float* type_emb = (const float*)d_in[3];
    const float* W1       = (const float*)d_in[4];
    const float* a_src1   = (const float*)d_in[5];
    const float* a_dst1   = (const float*)d_in[6];
    const float* b1       = (const float*)d_in[7];
    const float* W2       = (const float*)d_in[8];
    const float* a_src2   = (const float*)d_in[9];
    const float* a_dst2   = (const float*)d_in[10];
    const float* b2       = (const float*)d_in[11];
    const float* gamma    = (const float*)d_in[12];
    const float* beta     = (const float*)d_in[13];

    int N = in_sizes[0] / 5;
    int E = in_sizes[1] / 2;
    int EV = E + N;
    int NBKT = (N + BKT_NODES - 1) >> BKT_SHIFT;

    // Workspace layout (all 256B-aligned carves)
    char* base = (char*)d_ws;
    size_t off = 0;
    auto carve = [&](size_t bytes) { void* p = base + off; off += (bytes + 255) & ~(size_t)255; return p; };
    __half2* h1h = (__half2*)carve((size_t)N * 64 * sizeof(__half));
    __half2* h3h = (__half2*)carve((size_t)N * 64 * sizeof(__half));
    float* als1  = (float*)carve((size_t)N * 2 * sizeof(float));
    float* ald1  = (float*)carve((size_t)N * 2 * sizeof(float));
    float* als2  = (float*)carve((size_t)N * sizeof(float));
    float* ald2  = (float*)carve((size_t)N * sizeof(float));
    int*   rs    = (int*)carve((size_t)N * sizeof(int));
    int*   cur   = (int*)carve((size_t)N * sizeof(int));
    int*   bcnt  = (int*)carve(1024 * sizeof(int));
    int*   bst   = (int*)carve(1024 * sizeof(int));
    int*   ssrc  = (int*)carve((size_t)EV * sizeof(int));
    unsigned int* pk = (unsigned int*)carve((size_t)NBKT * BKT_CAP * sizeof(unsigned int));

    dim3 tb(256);
    dim3 nb((N + 3) / 4);

    // Node features + layer-1 logits
    k_node1<<<nb, tb, 0, stream>>>(x, type_ids, type_emb, W1, a_src1, a_dst1,
                                   h1h, als1, ald1, N);

    // CSR build (dst-sorted) via LDS-staged 256-node buckets
    hipMemsetAsync(bcnt, 0, NBKT * sizeof(int), stream);
    k_bucketA<<<dim3((EV + CHUNK - 1) / CHUNK), tb, 0, stream>>>(ei, pk, bcnt, E, EV, NBKT);
    k_bscan<<<dim3(1), dim3(1024), 0, stream>>>(bcnt, bst, NBKT);
    k_build<<<dim3(NBKT), tb, 0, stream>>>(pk, bcnt, bst, rs, cur, ssrc, N);

    // Fused layer-1 aggregate + W2 projection + layer-2 logits
    k_gather1<<<nb, tb, 0, stream>>>(rs, cur, ssrc, h1h, als1, ald1, b1, W2,
                                     a_src2, a_dst2, h3h, als2, ald2, N);
    // Layer-2 aggregate + LayerNorm
    k_gather2<<<nb, tb, 0, stream>>>(rs, cur, ssrc, h3h, als2, ald2, b2, gamma, beta,
                                     (float*)d_out, N);
}

// Round 6
// 375.711 us; speedup vs baseline: 3.7361x; 1.3660x over previous
//
#include <hip/hip_runtime.h>
#include <hip/hip_fp16.h>

#define NEG_SLOPE 0.2f
#define BKT_SHIFT 8
#define BKT_NODES 256
#define BKT_CAP 10240
#define SRC_SHIFT 18
#define SRC_MASK 0x3FFFF
#define CHUNK 4096
#define NBMAX 512

// ---------------- Kernel: node prep layer 1 ----------------
// h1 (fp16, row-major 64 halves/node) + layer-1 attention logits.
__global__ void k_node1(const float* __restrict__ x, const int* __restrict__ type_ids,
                        const float* __restrict__ type_emb, const float* __restrict__ W1,
                        const float* __restrict__ a_src1, const float* __restrict__ a_dst1,
                        __half2* __restrict__ h1h, float* __restrict__ als1, float* __restrict__ ald1,
                        int N)
{
    int node = blockIdx.x * 4 + (threadIdx.x >> 6);
    int j = threadIdx.x & 63;
    if (node >= N) return;

    float xin[21];
#pragma unroll
    for (int k = 0; k < 5; k++) xin[k] = x[node * 5 + k];
    int t = type_ids[node];
#pragma unroll
    for (int k = 0; k < 16; k++) xin[5 + k] = type_emb[t * 16 + k];

    float h = 0.f;
#pragma unroll
    for (int k = 0; k < 21; k++) h += xin[k] * W1[k * 64 + j];

    float hn = __shfl_xor(h, 1);
    if ((j & 1) == 0)
        h1h[node * 32 + (j >> 1)] = __floats2half2_rn(h, hn);

    int head = j >> 5, lane = j & 31;
    float ps = h * a_src1[head * 32 + lane];
    float pd = h * a_dst1[head * 32 + lane];
#pragma unroll
    for (int m = 16; m >= 1; m >>= 1) { ps += __shfl_xor(ps, m); pd += __shfl_xor(pd, m); }
    if (lane == 0) { als1[node * 2 + head] = ps; ald1[node * 2 + head] = pd; }
}

// ---------------- CSR build, phase A: LDS-staged bucket append (edges only) ----------------
__global__ void k_bucketA(const int* __restrict__ ei, unsigned int* __restrict__ pk,
                          int* __restrict__ bcnt, int E, int NBKT)
{
    __shared__ unsigned int stage[CHUNK];
    __shared__ unsigned short stageB[CHUNK];
    __shared__ int cnt[NBMAX];
    __shared__ int excl[NBMAX];
    __shared__ int curp[NBMAX];
    __shared__ int gbase[NBMAX];

    int t = threadIdx.x;
    int e0 = blockIdx.x * CHUNK;

    for (int i = t; i < NBMAX; i += 256) cnt[i] = 0;
    __syncthreads();

    for (int i = t; i < CHUNK; i += 256) {
        int e = e0 + i;
        if (e >= E) break;
        int d = ei[E + e];
        atomicAdd(&cnt[d >> BKT_SHIFT], 1);
    }
    __syncthreads();
    for (int i = t; i < NBMAX; i += 256) curp[i] = cnt[i];
    __syncthreads();
    for (int off = 1; off < NBMAX; off <<= 1) {
        int v0 = (t >= off) ? cnt[t - off] : 0;
        int v1 = (t + 256 >= off) ? cnt[t + 256 - off] : 0;
        __syncthreads();
        cnt[t] += v0; cnt[t + 256] += v1;
        __syncthreads();
    }
    for (int i = t; i < NBMAX; i += 256) {
        int o = curp[i];
        int ex = cnt[i] - o;
        excl[i] = ex;
        curp[i] = ex;
    }
    __syncthreads();
    for (int b = t; b < NBKT; b += 256) {
        int c = cnt[b] - excl[b];
        gbase[b] = (c > 0) ? atomicAdd(&bcnt[b], c) : 0;
    }
    __syncthreads();
    for (int i = t; i < CHUNK; i += 256) {
        int e = e0 + i;
        if (e >= E) break;
        int s = ei[e], d = ei[E + e];
        int b = d >> BKT_SHIFT;
        int p = atomicAdd(&curp[b], 1);
        stage[p] = (unsigned)s | ((unsigned)(d & (BKT_NODES - 1)) << SRC_SHIFT);
        stageB[p] = (unsigned short)b;
    }
    __syncthreads();
    int total = E - e0; if (total > CHUNK) total = CHUNK;
    for (int i = t; i < total; i += 256) {
        int b = stageB[i];
        int idx = gbase[b] + (i - excl[b]);
        if (idx < BKT_CAP) pk[(size_t)b * BKT_CAP + idx] = stage[i];
    }
}

// ---------------- CSR build, phase B: per-bucket counting sort (inline prefix) ----------------
__global__ void k_build(const unsigned int* __restrict__ pk, const int* __restrict__ bcnt,
                        int* __restrict__ rs, int* __restrict__ cur,
                        int* __restrict__ ssrc, int N)
{
    __shared__ int cnt[BKT_NODES];
    __shared__ int cursor[BKT_NODES];
    __shared__ int orig[BKT_NODES];
    __shared__ int red[256];
    int b = blockIdx.x;
    int t = threadIdx.x;
    int nb = min(bcnt[b], BKT_CAP);

    // inline exclusive prefix over earlier buckets
    int part = 0;
    for (int i = t; i < b; i += 256) part += min(bcnt[i], BKT_CAP);
    red[t] = part;
    cnt[t] = 0;
    __syncthreads();
    for (int off = 128; off; off >>= 1) {
        if (t < off) red[t] += red[t + off];
        __syncthreads();
    }
    int bs = red[0];

    const unsigned int* mypk = pk + (size_t)b * BKT_CAP;
    for (int e = t; e < nb; e += 256)
        atomicAdd(&cnt[mypk[e] >> SRC_SHIFT], 1);
    __syncthreads();
    orig[t] = cnt[t];
    __syncthreads();
    for (int off = 1; off < BKT_NODES; off <<= 1) {
        int v = (t >= off) ? cnt[t - off] : 0;
        __syncthreads();
        cnt[t] += v;
        __syncthreads();
    }
    {
        int c = orig[t];
        int ex = cnt[t] - c;
        cursor[t] = ex;
        int node = (b << BKT_SHIFT) + t;
        if (node < N) { rs[node] = bs + ex; cur[node] = bs + ex + c; }
    }
    __syncthreads();
    for (int e = t; e < nb; e += 256) {
        unsigned int w = mypk[e];
        int p = atomicAdd(&cursor[w >> SRC_SHIFT], 1);
        ssrc[bs + p] = (int)(w & SRC_MASK);
    }
}

// ---------------- Fused gather layer 1 + W2 projection + layer-2 logits ----------------
// Wave per node. lane = (eg = l>>3 edge slot, ch = l&7 channel octet).
// One dwordx4 per lane gathers 8 fp16 channels; a wave VMEM covers 8 edges.
__global__ void k_gather1(const int* __restrict__ rs, const int* __restrict__ cur,
                          const int* __restrict__ ssrc, const float4* __restrict__ h4,
                          const float* __restrict__ als1, const float* __restrict__ ald1,
                          const float* __restrict__ b1, const float* __restrict__ W2,
                          const float* __restrict__ a_src2, const float* __restrict__ a_dst2,
                          __half2* __restrict__ h3h, float* __restrict__ als2,
                          float* __restrict__ ald2, int N)
{
    __shared__ float sh[4][64];
    int wv = threadIdx.x >> 6;
    int node = blockIdx.x * 4 + wv;
    if (node >= N) return;
    int l = threadIdx.x & 63;
    int eg = l >> 3;
    int ch = l & 7;
    int head = ch >> 2;
    float ad = ald1[node * 2 + head];

    int beg = rs[node], end = cur[node];
    int cnt = end - beg;
    float acc[8] = {0.f,0.f,0.f,0.f,0.f,0.f,0.f,0.f};
    float wsum = 0.f;

    for (int base = 0; base < cnt; base += 16) {
        int o0 = base + eg, o1 = base + 8 + eg;
        bool v0 = o0 < cnt, v1 = o1 < cnt;
        int s0 = node, s1 = node;
        if (v0) s0 = ssrc[beg + o0];
        if (v1) s1 = ssrc[beg + o1];
        float al0 = als1[s0 * 2 + head];
        float al1 = als1[s1 * 2 + head];
        float4 r0 = h4[(size_t)s0 * 8 + ch];
        float4 r1 = h4[(size_t)s1 * 8 + ch];
        float lg0 = al0 + ad; lg0 = (lg0 >= 0.f) ? lg0 : NEG_SLOPE * lg0;
        float lg1 = al1 + ad; lg1 = (lg1 >= 0.f) ? lg1 : NEG_SLOPE * lg1;
        float w0 = v0 ? __expf(lg0) : 0.f;
        float w1 = v1 ? __expf(lg1) : 0.f;
        const __half2* p0 = (const __half2*)&r0;
        const __half2* p1 = (const __half2*)&r1;
#pragma unroll
        for (int q = 0; q < 4; q++) {
            float2 f0 = __half22float2(p0[q]);
            float2 f1 = __half22float2(p1[q]);
            acc[2*q]   += w0 * f0.x; acc[2*q+1] += w0 * f0.y;
            acc[2*q]   += w1 * f1.x; acc[2*q+1] += w1 * f1.y;
        }
        wsum += w0 + w1;
    }
    // reduce across edge slots (lane bits 3..5)
#pragma unroll
    for (int m = 8; m <= 32; m <<= 1) {
        wsum += __shfl_xor(wsum, m);
#pragma unroll
        for (int q = 0; q < 8; q++) acc[q] += __shfl_xor(acc[q], m);
    }
    // self loop
    {
        float lg = als1[node * 2 + head] + ad;
        lg = (lg >= 0.f) ? lg : NEG_SLOPE * lg;
        float w = __expf(lg);
        float4 r = h4[(size_t)node * 8 + ch];
        const __half2* p = (const __half2*)&r;
#pragma unroll
        for (int q = 0; q < 4; q++) {
            float2 f = __half22float2(p[q]);
            acc[2*q] += w * f.x; acc[2*q+1] += w * f.y;
        }
        wsum += w;
    }
    float inv = 1.f / (wsum + 1e-16f);
    if (eg == 0) {
#pragma unroll
        for (int q = 0; q < 8; q++)
            sh[wv][ch * 8 + q] = fmaxf(acc[q] * inv + b1[ch * 8 + q], 0.f);
    }
    // same-wave LDS RAW (writers lanes 0-7, readers all lanes of this wave)
    float h3 = 0.f;
#pragma unroll
    for (int k = 0; k < 64; k++)
        h3 += sh[wv][k] * W2[k * 64 + l];

    float hn = __shfl_xor(h3, 1);
    if ((l & 1) == 0)
        h3h[node * 32 + (l >> 1)] = __floats2half2_rn(h3, hn);

    float ps = h3 * a_src2[l];
    float pd = h3 * a_dst2[l];
#pragma unroll
    for (int m = 32; m >= 1; m >>= 1) { ps += __shfl_xor(ps, m); pd += __shfl_xor(pd, m); }
    if (l == 0) { als2[node] = ps; ald2[node] = pd; }
}

// ---------------- Gather layer 2 + LayerNorm ----------------
__global__ void k_gather2(const int* __restrict__ rs, const int* __restrict__ cur,
                          const int* __restrict__ ssrc, const float4* __restrict__ h4,
                          const float* __restrict__ als2, const float* __restrict__ ald2,
                          const float* __restrict__ b2, const float* __restrict__ gamma,
                          const float* __restrict__ beta, float* __restrict__ out, int N)
{
    int node = blockIdx.x * 4 + (threadIdx.x >> 6);
    if (node >= N) return;
    int l = threadIdx.x & 63;
    int eg = l >> 3;
    int ch = l & 7;
    float ad = ald2[node];

    int beg = rs[node], end = cur[node];
    int cnt = end - beg;
    float acc[8] = {0.f,0.f,0.f,0.f,0.f,0.f,0.f,0.f};
    float wsum = 0.f;

    for (int base = 0; base < cnt; base += 16) {
        int o0 = base + eg, o1 = base + 8 + eg;
        bool v0 = o0 < cnt, v1 = o1 < cnt;
        int s0 = node, s1 = node;
        if (v0) s0 = ssrc[beg + o0];
        if (v1) s1 = ssrc[beg + o1];
        float al0 = als2[s0];
        float al1 = als2[s1];
        float4 r0 = h4[(size_t)s0 * 8 + ch];
        float4 r1 = h4[(size_t)s1 * 8 + ch];
        float lg0 = al0 + ad; lg0 = (lg0 >= 0.f) ? lg0 : NEG_SLOPE * lg0;
        float lg1 = al1 + ad; lg1 = (lg1 >= 0.f) ? lg1 : NEG_SLOPE * lg1;
        float w0 = v0 ? __expf(lg0) : 0.f;
        float w1 = v1 ? __expf(lg1) : 0.f;
        const __half2* p0 = (const __half2*)&r0;
        const __half2* p1 = (const __half2*)&r1;
#pragma unroll
        for (int q = 0; q < 4; q++) {
            float2 f0 = __half22float2(p0[q]);
            float2 f1 = __half22float2(p1[q]);
            acc[2*q]   += w0 * f0.x; acc[2*q+1] += w0 * f0.y;
            acc[2*q]   += w1 * f1.x; acc[2*q+1] += w1 * f1.y;
        }
        wsum += w0 + w1;
    }
#pragma unroll
    for (int m = 8; m <= 32; m <<= 1) {
        wsum += __shfl_xor(wsum, m);
#pragma unroll
        for (int q = 0; q < 8; q++) acc[q] += __shfl_xor(acc[q], m);
    }
    // self loop
    {
        float lg = als2[node] + ad;
        lg = (lg >= 0.f) ? lg : NEG_SLOPE * lg;
        float w = __expf(lg);
        float4 r = h4[(size_t)node * 8 + ch];
        const __half2* p = (const __half2*)&r;
#pragma unroll
        for (int q = 0; q < 4; q++) {
            float2 f = __half22float2(p[q]);
            acc[2*q] += w * f.x; acc[2*q+1] += w * f.y;
        }
        wsum += w;
    }
    float inv = 1.f / (wsum + 1e-16f);
    float o[8];
    float s = 0.f;
#pragma unroll
    for (int q = 0; q < 8; q++) { o[q] = acc[q] * inv + b2[ch * 8 + q]; s += o[q]; }
#pragma unroll
    for (int m = 1; m <= 4; m <<= 1) s += __shfl_xor(s, m);
    float mu = s * (1.f / 64.f);
    float v = 0.f;
#pragma unroll
    for (int q = 0; q < 8; q++) { float d = o[q] - mu; v += d * d; }
#pragma unroll
    for (int m = 1; m <= 4; m <<= 1) v += __shfl_xor(v, m);
    v *= (1.f / 64.f);
    float r = rsqrtf(v + 1e-5f);
    if (eg == 0) {
        float res[8];
#pragma unroll
        for (int q = 0; q < 8; q++)
            res[q] = (o[q] - mu) * r * gamma[ch * 8 + q] + beta[ch * 8 + q];
        float4* op = (float4*)(out + (size_t)node * 64 + ch * 8);
        op[0] = make_float4(res[0], res[1], res[2], res[3]);
        op[1] = make_float4(res[4], res[5], res[6], res[7]);
    }
}

extern "C" void kernel_launch(void* const* d_in, const int* in_sizes, int n_in,
                              void* d_out, int out_size, void* d_ws, size_t ws_size,
                              hipStream_t stream) {
    const float* x        = (const float*)d_in[0];
    const int*   ei       = (const int*)  d_in[1];
    const int*   type_ids = (const int*)  d_in[2];
    const float* type_emb = (const float*)d_in[3];
    const float* W1       = (const float*)d_in[4];
    const float* a_src1   = (const float*)d_in[5];
    const float* a_dst1   = (const float*)d_in[6];
    const float* b1       = (const float*)d_in[7];
    const float* W2       = (const float*)d_in[8];
    const float* a_src2   = (const float*)d_in[9];
    const float* a_dst2   = (const float*)d_in[10];
    const float* b2       = (const float*)d_in[11];
    const float* gamma    = (const float*)d_in[12];
    const float* beta     = (const float*)d_in[13];

    int N = in_sizes[0] / 5;
    int E = in_sizes[1] / 2;
    int NBKT = (N + BKT_NODES - 1) >> BKT_SHIFT;

    // Workspace layout (256B-aligned carves)
    char* base = (char*)d_ws;
    size_t off = 0;
    auto carve = [&](size_t bytes) { void* p = base + off; off += (bytes + 255) & ~(size_t)255; return p; };
    __half2* h1h = (__half2*)carve((size_t)N * 64 * sizeof(__half));
    __half2* h3h = (__half2*)carve((size_t)N * 64 * sizeof(__half));
    float* als1  = (float*)carve((size_t)N * 2 * sizeof(float));
    float* ald1  = (float*)carve((size_t)N * 2 * sizeof(float));
    float* als2  = (float*)carve((size_t)N * sizeof(float));
    float* ald2  = (float*)carve((size_t)N * sizeof(float));
    int*   rs    = (int*)carve((size_t)N * sizeof(int));
    int*   cur   = (int*)carve((size_t)N * sizeof(int));
    int*   bcnt  = (int*)carve(1024 * sizeof(int));
    int*   ssrc  = (int*)carve((size_t)E * sizeof(int));
    unsigned int* pk = (unsigned int*)carve((size_t)NBKT * BKT_CAP * sizeof(unsigned int));

    dim3 tb(256);
    dim3 nb((N + 3) / 4);

    // Node features + layer-1 logits
    k_node1<<<nb, tb, 0, stream>>>(x, type_ids, type_emb, W1, a_src1, a_dst1,
                                   h1h, als1, ald1, N);

    // CSR build (dst-sorted, edges only; self-loops handled in gathers)
    hipMemsetAsync(bcnt, 0, NBKT * sizeof(int), stream);
    k_bucketA<<<dim3((E + CHUNK - 1) / CHUNK), tb, 0, stream>>>(ei, pk, bcnt, E, NBKT);
    k_build<<<dim3(NBKT), tb, 0, stream>>>(pk, bcnt, rs, cur, ssrc, N);

    // Fused layer-1 aggregate + W2 projection + layer-2 logits
    k_gather1<<<nb, tb, 0, stream>>>(rs, cur, ssrc, (const float4*)h1h, als1, ald1, b1, W2,
                                     a_src2, a_dst2, h3h, als2, ald2, N);
    // Layer-2 aggregate + LayerNorm
    k_gather2<<<nb, tb, 0, stream>>>(rs, cur, ssrc, (const float4*)h3h, als2, ald2, b2,
                                     gamma, beta, (float*)d_out, N);
}

// Round 8
// 345.410 us; speedup vs baseline: 4.0638x; 1.0877x over previous
//
#include <hip/hip_runtime.h>
#include <hip/hip_fp16.h>

#define NEG_SLOPE 0.2f
#define BKT_SHIFT 8
#define BKT_NODES 256
#define BKT_CAP 10240
#define SRC_SHIFT 18
#define SRC_MASK 0x3FFFF
#define CHUNK 4096
#define NBMAX 512

typedef _Float16 half8 __attribute__((ext_vector_type(8)));
typedef float float4v __attribute__((ext_vector_type(4)));

// ---------------- Kernel: node prep layer 1 ----------------
__global__ void k_node1(const float* __restrict__ x, const int* __restrict__ type_ids,
                        const float* __restrict__ type_emb, const float* __restrict__ W1,
                        const float* __restrict__ a_src1, const float* __restrict__ a_dst1,
                        __half2* __restrict__ h1h, float* __restrict__ als1, float* __restrict__ ald1,
                        int N)
{
    int node = blockIdx.x * 4 + (threadIdx.x >> 6);
    int j = threadIdx.x & 63;
    if (node >= N) return;

    float xin[21];
#pragma unroll
    for (int k = 0; k < 5; k++) xin[k] = x[node * 5 + k];
    int t = type_ids[node];
#pragma unroll
    for (int k = 0; k < 16; k++) xin[5 + k] = type_emb[t * 16 + k];

    float h = 0.f;
#pragma unroll
    for (int k = 0; k < 21; k++) h += xin[k] * W1[k * 64 + j];

    float hn = __shfl_xor(h, 1);
    if ((j & 1) == 0)
        h1h[node * 32 + (j >> 1)] = __floats2half2_rn(h, hn);

    int head = j >> 5, lane = j & 31;
    float ps = h * a_src1[head * 32 + lane];
    float pd = h * a_dst1[head * 32 + lane];
#pragma unroll
    for (int m = 16; m >= 1; m >>= 1) { ps += __shfl_xor(ps, m); pd += __shfl_xor(pd, m); }
    if (lane == 0) { als1[node * 2 + head] = ps; ald1[node * 2 + head] = pd; }
}

// ---------------- CSR build, phase A: LDS-staged bucket append ----------------
__global__ void k_bucketA(const int* __restrict__ ei, unsigned int* __restrict__ pk,
                          int* __restrict__ bcnt, int E, int NBKT)
{
    __shared__ unsigned int stage[CHUNK];
    __shared__ unsigned short stageB[CHUNK];
    __shared__ int cnt[NBMAX];
    __shared__ int excl[NBMAX];
    __shared__ int curp[NBMAX];
    __shared__ int gbase[NBMAX];

    int t = threadIdx.x;
    int e0 = blockIdx.x * CHUNK;

    for (int i = t; i < NBMAX; i += 256) cnt[i] = 0;
    __syncthreads();

    for (int i = t; i < CHUNK; i += 256) {
        int e = e0 + i;
        if (e >= E) break;
        int d = ei[E + e];
        atomicAdd(&cnt[d >> BKT_SHIFT], 1);
    }
    __syncthreads();
    for (int i = t; i < NBMAX; i += 256) curp[i] = cnt[i];
    __syncthreads();
    for (int off = 1; off < NBMAX; off <<= 1) {
        int v0 = (t >= off) ? cnt[t - off] : 0;
        int v1 = (t + 256 >= off) ? cnt[t + 256 - off] : 0;
        __syncthreads();
        cnt[t] += v0; cnt[t + 256] += v1;
        __syncthreads();
    }
    for (int i = t; i < NBMAX; i += 256) {
        int o = curp[i];
        int ex = cnt[i] - o;
        excl[i] = ex;
        curp[i] = ex;
    }
    __syncthreads();
    for (int b = t; b < NBKT; b += 256) {
        int c = cnt[b] - excl[b];
        gbase[b] = (c > 0) ? atomicAdd(&bcnt[b], c) : 0;
    }
    __syncthreads();
    for (int i = t; i < CHUNK; i += 256) {
        int e = e0 + i;
        if (e >= E) break;
        int s = ei[e], d = ei[E + e];
        int b = d >> BKT_SHIFT;
        int p = atomicAdd(&curp[b], 1);
        stage[p] = (unsigned)s | ((unsigned)(d & (BKT_NODES - 1)) << SRC_SHIFT);
        stageB[p] = (unsigned short)b;
    }
    __syncthreads();
    int total = E - e0; if (total > CHUNK) total = CHUNK;
    for (int i = t; i < total; i += 256) {
        int b = stageB[i];
        int idx = gbase[b] + (i - excl[b]);
        if (idx < BKT_CAP) pk[(size_t)b * BKT_CAP + idx] = stage[i];
    }
}

// ---------------- CSR build, phase B: per-bucket counting sort (LDS-stashed) ----------------
__global__ void k_build(const unsigned int* __restrict__ pk, const int* __restrict__ bcnt,
                        int* __restrict__ rs, int* __restrict__ cur,
                        int* __restrict__ ssrc, int N)
{
    __shared__ unsigned int vals[BKT_CAP];   // 40 KB: single global read of this bucket
    __shared__ int cnt[BKT_NODES];
    __shared__ int cursor[BKT_NODES];
    __shared__ int orig[BKT_NODES];
    __shared__ int red[256];
    int b = blockIdx.x;
    int t = threadIdx.x;
    int nb = min(bcnt[b], BKT_CAP);

    // inline exclusive prefix over earlier buckets
    int part = 0;
    for (int i = t; i < b; i += 256) part += min(bcnt[i], BKT_CAP);
    red[t] = part;
    cnt[t] = 0;
    __syncthreads();
    for (int off = 128; off; off >>= 1) {
        if (t < off) red[t] += red[t + off];
        __syncthreads();
    }
    int bs = red[0];

    const unsigned int* mypk = pk + (size_t)b * BKT_CAP;
    for (int e = t; e < nb; e += 256) {
        unsigned int v = mypk[e];
        vals[e] = v;
        atomicAdd(&cnt[v >> SRC_SHIFT], 1);
    }
    __syncthreads();
    orig[t] = cnt[t];
    __syncthreads();
    for (int off = 1; off < BKT_NODES; off <<= 1) {
        int v = (t >= off) ? cnt[t - off] : 0;
        __syncthreads();
        cnt[t] += v;
        __syncthreads();
    }
    {
        int c = orig[t];
        int ex = cnt[t] - c;
        cursor[t] = ex;
        int node = (b << BKT_SHIFT) + t;
        if (node < N) { rs[node] = bs + ex; cur[node] = bs + ex + c; }
    }
    __syncthreads();
    for (int e = t; e < nb; e += 256) {
        unsigned int w = vals[e];
        int p = atomicAdd(&cursor[w >> SRC_SHIFT], 1);
        ssrc[bs + p] = (int)(w & SRC_MASK);
    }
}

// ---------------- Gather layer 1 (gather-only -> h2 fp16) ----------------
__global__ void k_gather1(const int* __restrict__ rs, const int* __restrict__ cur,
                          const int* __restrict__ ssrc, const float4* __restrict__ h4,
                          const float* __restrict__ als1, const float* __restrict__ ald1,
                          const float* __restrict__ b1, float4* __restrict__ h2h4, int N)
{
    int node = blockIdx.x * 4 + (threadIdx.x >> 6);
    if (node >= N) return;
    int l = threadIdx.x & 63;
    int eg = l >> 3;
    int ch = l & 7;
    int head = ch >> 2;
    float ad = ald1[node * 2 + head];

    int beg = rs[node], end = cur[node];
    int cnt = end - beg;
    float acc[8] = {0.f,0.f,0.f,0.f,0.f,0.f,0.f,0.f};
    float wsum = 0.f;

    for (int base = 0; base < cnt; base += 16) {
        int o0 = base + eg, o1 = base + 8 + eg;
        bool v0 = o0 < cnt, v1 = o1 < cnt;
        int s0 = node, s1 = node;
        if (v0) s0 = ssrc[beg + o0];
        if (v1) s1 = ssrc[beg + o1];
        float al0 = als1[s0 * 2 + head];
        float al1 = als1[s1 * 2 + head];
        float4 r0 = h4[(size_t)s0 * 8 + ch];
        float4 r1 = h4[(size_t)s1 * 8 + ch];
        float lg0 = al0 + ad; lg0 = (lg0 >= 0.f) ? lg0 : NEG_SLOPE * lg0;
        float lg1 = al1 + ad; lg1 = (lg1 >= 0.f) ? lg1 : NEG_SLOPE * lg1;
        float w0 = v0 ? __expf(lg0) : 0.f;
        float w1 = v1 ? __expf(lg1) : 0.f;
        const __half2* p0 = (const __half2*)&r0;
        const __half2* p1 = (const __half2*)&r1;
#pragma unroll
        for (int q = 0; q < 4; q++) {
            float2 f0 = __half22float2(p0[q]);
            float2 f1 = __half22float2(p1[q]);
            acc[2*q]   += w0 * f0.x; acc[2*q+1] += w0 * f0.y;
            acc[2*q]   += w1 * f1.x; acc[2*q+1] += w1 * f1.y;
        }
        wsum += w0 + w1;
    }
#pragma unroll
    for (int m = 8; m <= 32; m <<= 1) {
        wsum += __shfl_xor(wsum, m);
#pragma unroll
        for (int q = 0; q < 8; q++) acc[q] += __shfl_xor(acc[q], m);
    }
    // self loop
    {
        float lg = als1[node * 2 + head] + ad;
        lg = (lg >= 0.f) ? lg : NEG_SLOPE * lg;
        float w = __expf(lg);
        float4 r = h4[(size_t)node * 8 + ch];
        const __half2* p = (const __half2*)&r;
#pragma unroll
        for (int q = 0; q < 4; q++) {
            float2 f = __half22float2(p[q]);
            acc[2*q] += w * f.x; acc[2*q+1] += w * f.y;
        }
        wsum += w;
    }
    float inv = 1.f / (wsum + 1e-16f);
    if (eg == 0) {
        union { float4 f4; __half2 h2[4]; } u;
#pragma unroll
        for (int q = 0; q < 4; q++) {
            float v0 = fmaxf(acc[2*q]   * inv + b1[ch * 8 + 2*q],     0.f);
            float v1 = fmaxf(acc[2*q+1] * inv + b1[ch * 8 + 2*q + 1], 0.f);
            u.h2[q] = __floats2half2_rn(v0, v1);
        }
        h2h4[(size_t)node * 8 + ch] = u.f4;
    }
}

// ---------------- MFMA projection: h3 = h2 @ W2 (fp16 in, fp32 acc) + logits ----------------
__global__ __launch_bounds__(256) void k_node2m(
        const _Float16* __restrict__ h2h, const float* __restrict__ W2,
        const float* __restrict__ a_src2, const float* __restrict__ a_dst2,
        _Float16* __restrict__ h3h, float* __restrict__ als2, float* __restrict__ ald2, int N)
{
    __shared__ _Float16 w2t[64][72];      // [n][k], padded
    __shared__ float h3t[4][16][65];      // per-wave [m][n] tile
    int t = threadIdx.x;
    for (int e = t; e < 4096; e += 256) {
        int k = e >> 6, n = e & 63;
        w2t[n][k] = (_Float16)W2[e];
    }
    __syncthreads();

    int w = t >> 6, l = t & 63;
    int l15 = l & 15, quad = l >> 4;
    int nodebase = blockIdx.x * 64 + w * 16;

    int arow = nodebase + l15;
    if (arow >= N) arow = N - 1;          // clamp: no OOB reads (results unused)
    const half8* ap = (const half8*)(h2h + (size_t)arow * 64 + quad * 8);
    half8 a0 = ap[0];      // k in [quad*8, quad*8+8)
    half8 a1 = ap[4];      // +32 halves
    float4v accs[4];
#pragma unroll
    for (int nt = 0; nt < 4; nt++) {
        half8 b0 = *(const half8*)(&w2t[nt * 16 + l15][quad * 8]);
        half8 b1 = *(const half8*)(&w2t[nt * 16 + l15][32 + quad * 8]);
        float4v c = {0.f, 0.f, 0.f, 0.f};
        c = __builtin_amdgcn_mfma_f32_16x16x32_f16(a0, b0, c, 0, 0, 0);
        c = __builtin_amdgcn_mfma_f32_16x16x32_f16(a1, b1, c, 0, 0, 0);
        accs[nt] = c;
    }
#pragma unroll
    for (int nt = 0; nt < 4; nt++)
#pragma unroll
        for (int r = 0; r < 4; r++)
            h3t[w][quad * 4 + r][nt * 16 + l15] = accs[nt][r];
    __syncthreads();

    int m = l >> 2, part = l & 3;
    int g = blockIdx.x * 64 + w * 16 + m;
    float ps = 0.f, pd = 0.f;
    union { float4 f4[2]; _Float16 h[16]; } u;
#pragma unroll
    for (int c = 0; c < 16; c++) {
        float v = h3t[w][m][part * 16 + c];
        ps += v * a_src2[part * 16 + c];
        pd += v * a_dst2[part * 16 + c];
        u.h[c] = (_Float16)v;
    }
    if (g < N) {
        float4* dst = (float4*)(h3h + (size_t)g * 64) + part * 2;
        dst[0] = u.f4[0];
        dst[1] = u.f4[1];
    }
    ps += __shfl_xor(ps, 1); ps += __shfl_xor(ps, 2);
    pd += __shfl_xor(pd, 1); pd += __shfl_xor(pd, 2);
    if (part == 0 && g < N) { als2[g] = ps; ald2[g] = pd; }
}

// ---------------- Gather layer 2 + LayerNorm ----------------
__global__ void k_gather2(const int* __restrict__ rs, const int* __restrict__ cur,
                          const int* __restrict__ ssrc, const float4* __restrict__ h4,
                          const float* __restrict__ als2, const float* __restrict__ ald2,
                          const float* __restrict__ b2, const float* __restrict__ gamma,
                          const float* __restrict__ beta, float* __restrict__ out, int N)
{
    int node = blockIdx.x * 4 + (threadIdx.x >> 6);
    if (node >= N) return;
    int l = threadIdx.x & 63;
    int eg = l >> 3;
    int ch = l & 7;
    float ad = ald2[node];

    int beg = rs[node], end = cur[node];
    int cnt = end - beg;
    float acc[8] = {0.f,0.f,0.f,0.f,0.f,0.f,0.f,0.f};
    float wsum = 0.f;

    for (int base = 0; base < cnt; base += 16) {
        int o0 = base + eg, o1 = base + 8 + eg;
        bool v0 = o0 < cnt, v1 = o1 < cnt;
        int s0 = node, s1 = node;
        if (v0) s0 = ssrc[beg + o0];
        if (v1) s1 = ssrc[beg + o1];
        float al0 = als2[s0];
        float al1 = als2[s1];
        float4 r0 = h4[(size_t)s0 * 8 + ch];
        float4 r1 = h4[(size_t)s1 * 8 + ch];
        float lg0 = al0 + ad; lg0 = (lg0 >= 0.f) ? lg0 : NEG_SLOPE * lg0;
        float lg1 = al1 + ad; lg1 = (lg1 >= 0.f) ? lg1 : NEG_SLOPE * lg1;
        float w0 = v0 ? __expf(lg0) : 0.f;
        float w1 = v1 ? __expf(lg1) : 0.f;
        const __half2* p0 = (const __half2*)&r0;
        const __half2* p1 = (const __half2*)&r1;
#pragma unroll
        for (int q = 0; q < 4; q++) {
            float2 f0 = __half22float2(p0[q]);
            float2 f1 = __half22float2(p1[q]);
            acc[2*q]   += w0 * f0.x; acc[2*q+1] += w0 * f0.y;
            acc[2*q]   += w1 * f1.x; acc[2*q+1] += w1 * f1.y;
        }
        wsum += w0 + w1;
    }
#pragma unroll
    for (int m = 8; m <= 32; m <<= 1) {
        wsum += __shfl_xor(wsum, m);
#pragma unroll
        for (int q = 0; q < 8; q++) acc[q] += __shfl_xor(acc[q], m);
    }
    // self loop
    {
        float lg = als2[node] + ad;
        lg = (lg >= 0.f) ? lg : NEG_SLOPE * lg;
        float w = __expf(lg);
        float4 r = h4[(size_t)node * 8 + ch];
        const __half2* p = (const __half2*)&r;
#pragma unroll
        for (int q = 0; q < 4; q++) {
            float2 f = __half22float2(p[q]);
            acc[2*q] += w * f.x; acc[2*q+1] += w * f.y;
        }
        wsum += w;
    }
    float inv = 1.f / (wsum + 1e-16f);
    float o[8];
    float s = 0.f;
#pragma unroll
    for (int q = 0; q < 8; q++) { o[q] = acc[q] * inv + b2[ch * 8 + q]; s += o[q]; }
#pragma unroll
    for (int m = 1; m <= 4; m <<= 1) s += __shfl_xor(s, m);
    float mu = s * (1.f / 64.f);
    float v = 0.f;
#pragma unroll
    for (int q = 0; q < 8; q++) { float d = o[q] - mu; v += d * d; }
#pragma unroll
    for (int m = 1; m <= 4; m <<= 1) v += __shfl_xor(v, m);
    v *= (1.f / 64.f);
    float r = rsqrtf(v + 1e-5f);
    if (eg == 0) {
        float res[8];
#pragma unroll
        for (int q = 0; q < 8; q++)
            res[q] = (o[q] - mu) * r * gamma[ch * 8 + q] + beta[ch * 8 + q];
        float4* op = (float4*)(out + (size_t)node * 64 + ch * 8);
        op[0] = make_float4(res[0], res[1], res[2], res[3]);
        op[1] = make_float4(res[4], res[5], res[6], res[7]);
    }
}

extern "C" void kernel_launch(void* const* d_in, const int* in_sizes, int n_in,
                              void* d_out, int out_size, void* d_ws, size_t ws_size,
                              hipStream_t stream) {
    const float* x        = (const float*)d_in[0];
    const int*   ei       = (const int*)  d_in[1];
    const int*   type_ids = (const int*)  d_in[2];
    const float* type_emb = (const float*)d_in[3];
    const float* W1       = (const float*)d_in[4];
    const float* a_src1   = (const float*)d_in[5];
    const float* a_dst1   = (const float*)d_in[6];
    const float* b1       = (const float*)d_in[7];
    const float* W2       = (const float*)d_in[8];
    const float* a_src2   = (const float*)d_in[9];
    const float* a_dst2   = (const float*)d_in[10];
    const float* b2       = (const float*)d_in[11];
    const float* gamma    = (const float*)d_in[12];
    const float* beta     = (const float*)d_in[13];

    int N = in_sizes[0] / 5;
    int E = in_sizes[1] / 2;
    int NBKT = (N + BKT_NODES - 1) >> BKT_SHIFT;

    // Workspace layout (256B-aligned carves).
    // pk (16 MB, dead after k_build) is overlaid on the h2h/h3h region (25.6 MB,
    // written only after k_build completes — stream-ordered). Total ~54 MB.
    char* base = (char*)d_ws;
    size_t off = 0;
    auto carve = [&](size_t bytes) { void* p = base + off; off += (bytes + 255) & ~(size_t)255; return p; };
    __half2* h1h = (__half2*)carve((size_t)N * 64 * sizeof(__half));
    size_t pk_bytes = (size_t)NBKT * BKT_CAP * sizeof(unsigned int);     // 16.0 MB
    size_t h23_bytes = 2 * (size_t)N * 64 * sizeof(__half);              // 25.6 MB
    char* uni = (char*)carve(pk_bytes > h23_bytes ? pk_bytes : h23_bytes);
    _Float16* h2h = (_Float16*)uni;
    _Float16* h3h = (_Float16*)(uni + (size_t)N * 64 * sizeof(__half));
    unsigned int* pk = (unsigned int*)uni;
    float* als1  = (float*)carve((size_t)N * 2 * sizeof(float));
    float* ald1  = (float*)carve((size_t)N * 2 * sizeof(float));
    float* als2  = (float*)carve((size_t)N * sizeof(float));
    float* ald2  = (float*)carve((size_t)N * sizeof(float));
    int*   rs    = (int*)carve((size_t)N * sizeof(int));
    int*   cur   = (int*)carve((size_t)N * sizeof(int));
    int*   bcnt  = (int*)carve(1024 * sizeof(int));
    int*   ssrc  = (int*)carve((size_t)E * sizeof(int));

    dim3 tb(256);
    dim3 nb((N + 3) / 4);

    // Node features + layer-1 logits
    k_node1<<<nb, tb, 0, stream>>>(x, type_ids, type_emb, W1, a_src1, a_dst1,
                                   h1h, als1, ald1, N);

    // CSR build (dst-sorted, edges only; self-loops handled in gathers)
    hipMemsetAsync(bcnt, 0, NBKT * sizeof(int), stream);
    k_bucketA<<<dim3((E + CHUNK - 1) / CHUNK), tb, 0, stream>>>(ei, pk, bcnt, E, NBKT);
    k_build<<<dim3(NBKT), tb, 0, stream>>>(pk, bcnt, rs, cur, ssrc, N);

    // Layer-1 aggregate -> h2 (fp16; overwrites pk, which is dead)
    k_gather1<<<nb, tb, 0, stream>>>(rs, cur, ssrc, (const float4*)h1h, als1, ald1, b1,
                                     (float4*)h2h, N);
    // MFMA projection + layer-2 logits
    k_node2m<<<dim3((N + 63) / 64), tb, 0, stream>>>(h2h, W2, a_src2, a_dst2,
                                                     h3h, als2, ald2, N);
    // Layer-2 aggregate + LayerNorm
    k_gather2<<<nb, tb, 0, stream>>>(rs, cur, ssrc, (const float4*)h3h, als2, ald2, b2,
                                     gamma, beta, (float*)d_out, N);
}

// Round 9
// 331.698 us; speedup vs baseline: 4.2318x; 1.0413x over previous
//
#include <hip/hip_runtime.h>
#include <hip/hip_fp16.h>

#define NEG_SLOPE 0.2f
#define BKT_SHIFT 8
#define BKT_NODES 256
#define BKT_CAP 10240
#define SRC_SHIFT 18
#define SRC_MASK 0x3FFFF
#define CHUNK 4096
#define NBMAX 512

typedef _Float16 half8 __attribute__((ext_vector_type(8)));
typedef float float4v __attribute__((ext_vector_type(4)));

// ---------------- Kernel: node prep layer 1 ----------------
__global__ void k_node1(const float* __restrict__ x, const int* __restrict__ type_ids,
                        const float* __restrict__ type_emb, const float* __restrict__ W1,
                        const float* __restrict__ a_src1, const float* __restrict__ a_dst1,
                        __half2* __restrict__ h1h, float* __restrict__ als1, float* __restrict__ ald1,
                        int N)
{
    int node = blockIdx.x * 4 + (threadIdx.x >> 6);
    int j = threadIdx.x & 63;
    if (node >= N) return;

    float xin[21];
#pragma unroll
    for (int k = 0; k < 5; k++) xin[k] = x[node * 5 + k];
    int t = type_ids[node];
#pragma unroll
    for (int k = 0; k < 16; k++) xin[5 + k] = type_emb[t * 16 + k];

    float h = 0.f;
#pragma unroll
    for (int k = 0; k < 21; k++) h += xin[k] * W1[k * 64 + j];

    float hn = __shfl_xor(h, 1);
    if ((j & 1) == 0)
        h1h[node * 32 + (j >> 1)] = __floats2half2_rn(h, hn);

    int head = j >> 5, lane = j & 31;
    float ps = h * a_src1[head * 32 + lane];
    float pd = h * a_dst1[head * 32 + lane];
#pragma unroll
    for (int m = 16; m >= 1; m >>= 1) { ps += __shfl_xor(ps, m); pd += __shfl_xor(pd, m); }
    if (lane == 0) { als1[node * 2 + head] = ps; ald1[node * 2 + head] = pd; }
}

// ---------------- CSR build, phase A: LDS-staged bucket append ----------------
__global__ void k_bucketA(const int* __restrict__ ei, unsigned int* __restrict__ pk,
                          int* __restrict__ bcnt, int E, int NBKT)
{
    __shared__ unsigned int stage[CHUNK];
    __shared__ unsigned short stageB[CHUNK];
    __shared__ int cnt[NBMAX];
    __shared__ int excl[NBMAX];
    __shared__ int curp[NBMAX];
    __shared__ int gbase[NBMAX];

    int t = threadIdx.x;
    int e0 = blockIdx.x * CHUNK;
    bool vec4 = ((E & 3) == 0);

    for (int i = t; i < NBMAX; i += 256) cnt[i] = 0;
    __syncthreads();

    // pass 1: count (int4 when aligned)
    if (vec4) {
        for (int i = t * 4; i < CHUNK; i += 1024) {
            int e = e0 + i;
            if (e >= E) break;
            int4 d4 = *(const int4*)(ei + (size_t)E + e);
            atomicAdd(&cnt[d4.x >> BKT_SHIFT], 1);
            atomicAdd(&cnt[d4.y >> BKT_SHIFT], 1);
            atomicAdd(&cnt[d4.z >> BKT_SHIFT], 1);
            atomicAdd(&cnt[d4.w >> BKT_SHIFT], 1);
        }
    } else {
        for (int i = t; i < CHUNK; i += 256) {
            int e = e0 + i;
            if (e >= E) break;
            atomicAdd(&cnt[ei[E + e] >> BKT_SHIFT], 1);
        }
    }
    __syncthreads();
    for (int i = t; i < NBMAX; i += 256) curp[i] = cnt[i];
    __syncthreads();
    for (int off = 1; off < NBMAX; off <<= 1) {
        int v0 = (t >= off) ? cnt[t - off] : 0;
        int v1 = (t + 256 >= off) ? cnt[t + 256 - off] : 0;
        __syncthreads();
        cnt[t] += v0; cnt[t + 256] += v1;
        __syncthreads();
    }
    for (int i = t; i < NBMAX; i += 256) {
        int o = curp[i];
        int ex = cnt[i] - o;
        excl[i] = ex;
        curp[i] = ex;
    }
    __syncthreads();
    for (int b = t; b < NBKT; b += 256) {
        int c = cnt[b] - excl[b];
        gbase[b] = (c > 0) ? atomicAdd(&bcnt[b], c) : 0;
    }
    __syncthreads();
    // pass 2: LDS scatter (int4 when aligned)
    if (vec4) {
        for (int i = t * 4; i < CHUNK; i += 1024) {
            int e = e0 + i;
            if (e >= E) break;
            int4 s4 = *(const int4*)(ei + e);
            int4 d4 = *(const int4*)(ei + (size_t)E + e);
            int ss[4] = {s4.x, s4.y, s4.z, s4.w};
            int dd[4] = {d4.x, d4.y, d4.z, d4.w};
#pragma unroll
            for (int k = 0; k < 4; k++) {
                int b = dd[k] >> BKT_SHIFT;
                int p = atomicAdd(&curp[b], 1);
                stage[p] = (unsigned)ss[k] | ((unsigned)(dd[k] & (BKT_NODES - 1)) << SRC_SHIFT);
                stageB[p] = (unsigned short)b;
            }
        }
    } else {
        for (int i = t; i < CHUNK; i += 256) {
            int e = e0 + i;
            if (e >= E) break;
            int s = ei[e], d = ei[E + e];
            int b = d >> BKT_SHIFT;
            int p = atomicAdd(&curp[b], 1);
            stage[p] = (unsigned)s | ((unsigned)(d & (BKT_NODES - 1)) << SRC_SHIFT);
            stageB[p] = (unsigned short)b;
        }
    }
    __syncthreads();
    int total = E - e0; if (total > CHUNK) total = CHUNK;
    for (int i = t; i < total; i += 256) {
        int b = stageB[i];
        int idx = gbase[b] + (i - excl[b]);
        if (idx < BKT_CAP) pk[(size_t)b * BKT_CAP + idx] = stage[i];
    }
}

// ---------------- CSR build, phase B: per-bucket counting sort (LDS-stashed) ----------------
__global__ void k_build(const unsigned int* __restrict__ pk, const int* __restrict__ bcnt,
                        int* __restrict__ rs, int* __restrict__ cur,
                        int* __restrict__ ssrc, int N)
{
    __shared__ unsigned int vals[BKT_CAP];
    __shared__ int cnt[BKT_NODES];
    __shared__ int cursor[BKT_NODES];
    __shared__ int orig[BKT_NODES];
    __shared__ int red[256];
    int b = blockIdx.x;
    int t = threadIdx.x;
    int nb = min(bcnt[b], BKT_CAP);

    int part = 0;
    for (int i = t; i < b; i += 256) part += min(bcnt[i], BKT_CAP);
    red[t] = part;
    cnt[t] = 0;
    __syncthreads();
    for (int off = 128; off; off >>= 1) {
        if (t < off) red[t] += red[t + off];
        __syncthreads();
    }
    int bs = red[0];

    const unsigned int* mypk = pk + (size_t)b * BKT_CAP;
    for (int e = t; e < nb; e += 256) {
        unsigned int v = mypk[e];
        vals[e] = v;
        atomicAdd(&cnt[v >> SRC_SHIFT], 1);
    }
    __syncthreads();
    orig[t] = cnt[t];
    __syncthreads();
    for (int off = 1; off < BKT_NODES; off <<= 1) {
        int v = (t >= off) ? cnt[t - off] : 0;
        __syncthreads();
        cnt[t] += v;
        __syncthreads();
    }
    {
        int c = orig[t];
        int ex = cnt[t] - c;
        cursor[t] = ex;
        int node = (b << BKT_SHIFT) + t;
        if (node < N) { rs[node] = bs + ex; cur[node] = bs + ex + c; }
    }
    __syncthreads();
    for (int e = t; e < nb; e += 256) {
        unsigned int w = vals[e];
        int p = atomicAdd(&cursor[w >> SRC_SHIFT], 1);
        ssrc[bs + p] = (int)(w & SRC_MASK);
    }
}

// ---------------- Gather layer 1 (packed-fp16 accumulate -> h2 fp16) ----------------
__global__ void k_gather1(const int* __restrict__ rs, const int* __restrict__ cur,
                          const int* __restrict__ ssrc, const float4* __restrict__ h4,
                          const float* __restrict__ als1, const float* __restrict__ ald1,
                          const float* __restrict__ b1, float4* __restrict__ h2h4, int N)
{
    int node = blockIdx.x * 4 + (threadIdx.x >> 6);
    if (node >= N) return;
    int l = threadIdx.x & 63;
    int eg = l >> 3;
    int ch = l & 7;
    int head = ch >> 2;
    float ad = ald1[node * 2 + head];

    int beg = rs[node], end = cur[node];
    int cnt = end - beg;
    __half2 acc2[4];
    acc2[0] = acc2[1] = acc2[2] = acc2[3] = __float2half2_rn(0.f);
    float wsum = 0.f;

    for (int base = 0; base < cnt; base += 16) {
        int o0 = base + eg, o1 = base + 8 + eg;
        bool v0 = o0 < cnt, v1 = o1 < cnt;
        int s0 = node, s1 = node;
        if (v0) s0 = ssrc[beg + o0];
        if (v1) s1 = ssrc[beg + o1];
        float al0 = als1[s0 * 2 + head];
        float al1 = als1[s1 * 2 + head];
        float4 r0 = h4[(size_t)s0 * 8 + ch];
        float4 r1 = h4[(size_t)s1 * 8 + ch];
        float lg0 = al0 + ad; lg0 = (lg0 >= 0.f) ? lg0 : NEG_SLOPE * lg0;
        float lg1 = al1 + ad; lg1 = (lg1 >= 0.f) ? lg1 : NEG_SLOPE * lg1;
        float w0 = v0 ? __expf(lg0) : 0.f;
        float w1 = v1 ? __expf(lg1) : 0.f;
        __half2 wh0 = __float2half2_rn(w0);
        __half2 wh1 = __float2half2_rn(w1);
        const __half2* p0 = (const __half2*)&r0;
        const __half2* p1 = (const __half2*)&r1;
#pragma unroll
        for (int q = 0; q < 4; q++) {
            acc2[q] = __hfma2(p0[q], wh0, acc2[q]);
            acc2[q] = __hfma2(p1[q], wh1, acc2[q]);
        }
        wsum += w0 + w1;
    }
    float acc[8];
#pragma unroll
    for (int q = 0; q < 4; q++) {
        float2 f = __half22float2(acc2[q]);
        acc[2*q] = f.x; acc[2*q+1] = f.y;
    }
#pragma unroll
    for (int m = 8; m <= 32; m <<= 1) {
        wsum += __shfl_xor(wsum, m);
#pragma unroll
        for (int q = 0; q < 8; q++) acc[q] += __shfl_xor(acc[q], m);
    }
    // self loop (fp32)
    {
        float lg = als1[node * 2 + head] + ad;
        lg = (lg >= 0.f) ? lg : NEG_SLOPE * lg;
        float w = __expf(lg);
        float4 r = h4[(size_t)node * 8 + ch];
        const __half2* p = (const __half2*)&r;
#pragma unroll
        for (int q = 0; q < 4; q++) {
            float2 f = __half22float2(p[q]);
            acc[2*q] += w * f.x; acc[2*q+1] += w * f.y;
        }
        wsum += w;
    }
    float inv = 1.f / (wsum + 1e-16f);
    if (eg == 0) {
        union { float4 f4; __half2 h2[4]; } u;
#pragma unroll
        for (int q = 0; q < 4; q++) {
            float v0 = fmaxf(acc[2*q]   * inv + b1[ch * 8 + 2*q],     0.f);
            float v1 = fmaxf(acc[2*q+1] * inv + b1[ch * 8 + 2*q + 1], 0.f);
            u.h2[q] = __floats2half2_rn(v0, v1);
        }
        h2h4[(size_t)node * 8 + ch] = u.f4;
    }
}

// ---------------- MFMA projection: h3 = h2 @ W2 (fp16 in, fp32 acc) + logits ----------------
__global__ __launch_bounds__(256) void k_node2m(
        const _Float16* __restrict__ h2h, const float* __restrict__ W2,
        const float* __restrict__ a_src2, const float* __restrict__ a_dst2,
        _Float16* __restrict__ h3h, float* __restrict__ als2, float* __restrict__ ald2, int N)
{
    __shared__ _Float16 w2t[64][72];
    __shared__ float h3t[4][16][65];
    int t = threadIdx.x;
    for (int e = t; e < 4096; e += 256) {
        int k = e >> 6, n = e & 63;
        w2t[n][k] = (_Float16)W2[e];
    }
    __syncthreads();

    int w = t >> 6, l = t & 63;
    int l15 = l & 15, quad = l >> 4;
    int nodebase = blockIdx.x * 64 + w * 16;

    int arow = nodebase + l15;
    if (arow >= N) arow = N - 1;
    const half8* ap = (const half8*)(h2h + (size_t)arow * 64 + quad * 8);
    half8 a0 = ap[0];
    half8 a1 = ap[4];
    float4v accs[4];
#pragma unroll
    for (int nt = 0; nt < 4; nt++) {
        half8 b0 = *(const half8*)(&w2t[nt * 16 + l15][quad * 8]);
        half8 b1 = *(const half8*)(&w2t[nt * 16 + l15][32 + quad * 8]);
        float4v c = {0.f, 0.f, 0.f, 0.f};
        c = __builtin_amdgcn_mfma_f32_16x16x32_f16(a0, b0, c, 0, 0, 0);
        c = __builtin_amdgcn_mfma_f32_16x16x32_f16(a1, b1, c, 0, 0, 0);
        accs[nt] = c;
    }
#pragma unroll
    for (int nt = 0; nt < 4; nt++)
#pragma unroll
        for (int r = 0; r < 4; r++)
            h3t[w][quad * 4 + r][nt * 16 + l15] = accs[nt][r];
    __syncthreads();

    int m = l >> 2, part = l & 3;
    int g = blockIdx.x * 64 + w * 16 + m;
    float ps = 0.f, pd = 0.f;
    union { float4 f4[2]; _Float16 h[16]; } u;
#pragma unroll
    for (int c = 0; c < 16; c++) {
        float v = h3t[w][m][part * 16 + c];
        ps += v * a_src2[part * 16 + c];
        pd += v * a_dst2[part * 16 + c];
        u.h[c] = (_Float16)v;
    }
    if (g < N) {
        float4* dst = (float4*)(h3h + (size_t)g * 64) + part * 2;
        dst[0] = u.f4[0];
        dst[1] = u.f4[1];
    }
    ps += __shfl_xor(ps, 1); ps += __shfl_xor(ps, 2);
    pd += __shfl_xor(pd, 1); pd += __shfl_xor(pd, 2);
    if (part == 0 && g < N) { als2[g] = ps; ald2[g] = pd; }
}

// ---------------- Gather layer 2 (packed-fp16 accumulate) + LayerNorm ----------------
__global__ void k_gather2(const int* __restrict__ rs, const int* __restrict__ cur,
                          const int* __restrict__ ssrc, const float4* __restrict__ h4,
                          const float* __restrict__ als2, const float* __restrict__ ald2,
                          const float* __restrict__ b2, const float* __restrict__ gamma,
                          const float* __restrict__ beta, float* __restrict__ out, int N)
{
    int node = blockIdx.x * 4 + (threadIdx.x >> 6);
    if (node >= N) return;
    int l = threadIdx.x & 63;
    int eg = l >> 3;
    int ch = l & 7;
    float ad = ald2[node];

    int beg = rs[node], end = cur[node];
    int cnt = end - beg;
    __half2 acc2[4];
    acc2[0] = acc2[1] = acc2[2] = acc2[3] = __float2half2_rn(0.f);
    float wsum = 0.f;

    for (int base = 0; base < cnt; base += 16) {
        int o0 = base + eg, o1 = base + 8 + eg;
        bool v0 = o0 < cnt, v1 = o1 < cnt;
        int s0 = node, s1 = node;
        if (v0) s0 = ssrc[beg + o0];
        if (v1) s1 = ssrc[beg + o1];
        float al0 = als2[s0];
        float al1 = als2[s1];
        float4 r0 = h4[(size_t)s0 * 8 + ch];
        float4 r1 = h4[(size_t)s1 * 8 + ch];
        float lg0 = al0 + ad; lg0 = (lg0 >= 0.f) ? lg0 : NEG_SLOPE * lg0;
        float lg1 = al1 + ad; lg1 = (lg1 >= 0.f) ? lg1 : NEG_SLOPE * lg1;
        float w0 = v0 ? __expf(lg0) : 0.f;
        float w1 = v1 ? __expf(lg1) : 0.f;
        __half2 wh0 = __float2half2_rn(w0);
        __half2 wh1 = __float2half2_rn(w1);
        const __half2* p0 = (const __half2*)&r0;
        const __half2* p1 = (const __half2*)&r1;
#pragma unroll
        for (int q = 0; q < 4; q++) {
            acc2[q] = __hfma2(p0[q], wh0, acc2[q]);
            acc2[q] = __hfma2(p1[q], wh1, acc2[q]);
        }
        wsum += w0 + w1;
    }
    float acc[8];
#pragma unroll
    for (int q = 0; q < 4; q++) {
        float2 f = __half22float2(acc2[q]);
        acc[2*q] = f.x; acc[2*q+1] = f.y;
    }
#pragma unroll
    for (int m = 8; m <= 32; m <<= 1) {
        wsum += __shfl_xor(wsum, m);
#pragma unroll
        for (int q = 0; q < 8; q++) acc[q] += __shfl_xor(acc[q], m);
    }
    // self loop (fp32)
    {
        float lg = als2[node] + ad;
        lg = (lg >= 0.f) ? lg : NEG_SLOPE * lg;
        float w = __expf(lg);
        float4 r = h4[(size_t)node * 8 + ch];
        const __half2* p = (const __half2*)&r;
#pragma unroll
        for (int q = 0; q < 4; q++) {
            float2 f = __half22float2(p[q]);
            acc[2*q] += w * f.x; acc[2*q+1] += w * f.y;
        }
        wsum += w;
    }
    float inv = 1.f / (wsum + 1e-16f);
    float o[8];
    float s = 0.f;
#pragma unroll
    for (int q = 0; q < 8; q++) { o[q] = acc[q] * inv + b2[ch * 8 + q]; s += o[q]; }
#pragma unroll
    for (int m = 1; m <= 4; m <<= 1) s += __shfl_xor(s, m);
    float mu = s * (1.f / 64.f);
    float v = 0.f;
#pragma unroll
    for (int q = 0; q < 8; q++) { float d = o[q] - mu; v += d * d; }
#pragma unroll
    for (int m = 1; m <= 4; m <<= 1) v += __shfl_xor(v, m);
    v *= (1.f / 64.f);
    float r = rsqrtf(v + 1e-5f);
    if (eg == 0) {
        float res[8];
#pragma unroll
        for (int q = 0; q < 8; q++)
            res[q] = (o[q] - mu) * r * gamma[ch * 8 + q] + beta[ch * 8 + q];
        float4* op = (float4*)(out + (size_t)node * 64 + ch * 8);
        op[0] = make_float4(res[0], res[1], res[2], res[3]);
        op[1] = make_float4(res[4], res[5], res[6], res[7]);
    }
}

extern "C" void kernel_launch(void* const* d_in, const int* in_sizes, int n_in,
                              void* d_out, int out_size, void* d_ws, size_t ws_size,
                              hipStream_t stream) {
    const float* x        = (const float*)d_in[0];
    const int*   ei       = (const int*)  d_in[1];
    const int*   type_ids = (const int*)  d_in[2];
    const float* type_emb = (const float*)d_in[3];
    const float* W1       = (const float*)d_in[4];
    const float* a_src1   = (const float*)d_in[5];
    const float* a_dst1   = (const float*)d_in[6];
    const float* b1       = (const float*)d_in[7];
    const float* W2       = (const float*)d_in[8];
    const float* a_src2   = (const float*)d_in[9];
    const float* a_dst2   = (const float*)d_in[10];
    const float* b2       = (const float*)d_in[11];
    const float* gamma    = (const float*)d_in[12];
    const float* beta     = (const float*)d_in[13];

    int N = in_sizes[0] / 5;
    int E = in_sizes[1] / 2;
    int NBKT = (N + BKT_NODES - 1) >> BKT_SHIFT;

    // Workspace: pk (16 MB, dead after k_build) overlaid on h2h/h3h (25.6 MB).
    char* base = (char*)d_ws;
    size_t off = 0;
    auto carve = [&](size_t bytes) { void* p = base + off; off += (bytes + 255) & ~(size_t)255; return p; };
    __half2* h1h = (__half2*)carve((size_t)N * 64 * sizeof(__half));
    size_t pk_bytes = (size_t)NBKT * BKT_CAP * sizeof(unsigned int);
    size_t h23_bytes = 2 * (size_t)N * 64 * sizeof(__half);
    char* uni = (char*)carve(pk_bytes > h23_bytes ? pk_bytes : h23_bytes);
    _Float16* h2h = (_Float16*)uni;
    _Float16* h3h = (_Float16*)(uni + (size_t)N * 64 * sizeof(__half));
    unsigned int* pk = (unsigned int*)uni;
    float* als1  = (float*)carve((size_t)N * 2 * sizeof(float));
    float* ald1  = (float*)carve((size_t)N * 2 * sizeof(float));
    float* als2  = (float*)carve((size_t)N * sizeof(float));
    float* ald2  = (float*)carve((size_t)N * sizeof(float));
    int*   rs    = (int*)carve((size_t)N * sizeof(int));
    int*   cur   = (int*)carve((size_t)N * sizeof(int));
    int*   bcnt  = (int*)carve(1024 * sizeof(int));
    int*   ssrc  = (int*)carve((size_t)E * sizeof(int));

    dim3 tb(256);
    dim3 nb((N + 3) / 4);

    k_node1<<<nb, tb, 0, stream>>>(x, type_ids, type_emb, W1, a_src1, a_dst1,
                                   h1h, als1, ald1, N);

    hipMemsetAsync(bcnt, 0, NBKT * sizeof(int), stream);
    k_bucketA<<<dim3((E + CHUNK - 1) / CHUNK), tb, 0, stream>>>(ei, pk, bcnt, E, NBKT);
    k_build<<<dim3(NBKT), tb, 0, stream>>>(pk, bcnt, rs, cur, ssrc, N);

    k_gather1<<<nb, tb, 0, stream>>>(rs, cur, ssrc, (const float4*)h1h, als1, ald1, b1,
                                     (float4*)h2h, N);
    k_node2m<<<dim3((N + 63) / 64), tb, 0, stream>>>(h2h, W2, a_src2, a_dst2,
                                                     h3h, als2, ald2, N);
    k_gather2<<<nb, tb, 0, stream>>>(rs, cur, ssrc, (const float4*)h3h, als2, ald2, b2,
                                     gamma, beta, (float*)d_out, N);
}

// Round 10
// 314.435 us; speedup vs baseline: 4.4641x; 1.0549x over previous
//
#include <hip/hip_runtime.h>
#include <hip/hip_fp16.h>

#define NEG_SLOPE 0.2f
#define BKT_SHIFT 8
#define BKT_NODES 256
#define BKT_CAP 10240
#define SRC_SHIFT 18
#define SRC_MASK 0x3FFFF
#define CHUNK 4096
#define NBMAX 512

typedef _Float16 half8 __attribute__((ext_vector_type(8)));
typedef float float4v __attribute__((ext_vector_type(4)));

// ---------------- Kernel: node prep layer 1 ----------------
__global__ void k_node1(const float* __restrict__ x, const int* __restrict__ type_ids,
                        const float* __restrict__ type_emb, const float* __restrict__ W1,
                        const float* __restrict__ a_src1, const float* __restrict__ a_dst1,
                        __half2* __restrict__ h1h, float* __restrict__ als1, float* __restrict__ ald1,
                        int N)
{
    int node = blockIdx.x * 4 + (threadIdx.x >> 6);
    int j = threadIdx.x & 63;
    if (node >= N) return;

    float xin[21];
#pragma unroll
    for (int k = 0; k < 5; k++) xin[k] = x[node * 5 + k];
    int t = type_ids[node];
#pragma unroll
    for (int k = 0; k < 16; k++) xin[5 + k] = type_emb[t * 16 + k];

    float h = 0.f;
#pragma unroll
    for (int k = 0; k < 21; k++) h += xin[k] * W1[k * 64 + j];

    float hn = __shfl_xor(h, 1);
    if ((j & 1) == 0)
        h1h[node * 32 + (j >> 1)] = __floats2half2_rn(h, hn);

    int head = j >> 5, lane = j & 31;
    float ps = h * a_src1[head * 32 + lane];
    float pd = h * a_dst1[head * 32 + lane];
#pragma unroll
    for (int m = 16; m >= 1; m >>= 1) { ps += __shfl_xor(ps, m); pd += __shfl_xor(pd, m); }
    if (lane == 0) { als1[node * 2 + head] = ps; ald1[node * 2 + head] = pd; }
}

// ---------------- CSR build, phase A: single-pass register-staged bucket append ----------------
__global__ void k_bucketA(const int* __restrict__ ei, unsigned int* __restrict__ pk,
                          int* __restrict__ bcnt, int E, int NBKT)
{
    __shared__ unsigned int stage[CHUNK];
    __shared__ unsigned short stageB[CHUNK];
    __shared__ int cnt[NBMAX];
    __shared__ int excl[NBMAX];
    __shared__ int curp[NBMAX];
    __shared__ int gbase[NBMAX];

    int t = threadIdx.x;
    int e0 = blockIdx.x * CHUNK;
    bool vec4 = ((E & 3) == 0);

    for (int i = t; i < NBMAX; i += 256) cnt[i] = 0;
    __syncthreads();

    int4 s4[4], d4[4];
    bool val[4];

    if (vec4) {
        // single read: stage 16 edges/thread in registers, count
#pragma unroll
        for (int it = 0; it < 4; it++) {
            int e = e0 + it * 1024 + t * 4;
            val[it] = (e < E);
            if (val[it]) {
                s4[it] = *(const int4*)(ei + e);
                d4[it] = *(const int4*)(ei + (size_t)E + e);
                atomicAdd(&cnt[d4[it].x >> BKT_SHIFT], 1);
                atomicAdd(&cnt[d4[it].y >> BKT_SHIFT], 1);
                atomicAdd(&cnt[d4[it].z >> BKT_SHIFT], 1);
                atomicAdd(&cnt[d4[it].w >> BKT_SHIFT], 1);
            }
        }
    } else {
        for (int i = t; i < CHUNK; i += 256) {
            int e = e0 + i;
            if (e >= E) break;
            atomicAdd(&cnt[ei[E + e] >> BKT_SHIFT], 1);
        }
    }
    __syncthreads();
    for (int i = t; i < NBMAX; i += 256) curp[i] = cnt[i];
    __syncthreads();
    for (int off = 1; off < NBMAX; off <<= 1) {
        int v0 = (t >= off) ? cnt[t - off] : 0;
        int v1 = (t + 256 >= off) ? cnt[t + 256 - off] : 0;
        __syncthreads();
        cnt[t] += v0; cnt[t + 256] += v1;
        __syncthreads();
    }
    for (int i = t; i < NBMAX; i += 256) {
        int o = curp[i];
        int ex = cnt[i] - o;
        excl[i] = ex;
        curp[i] = ex;
    }
    __syncthreads();
    for (int b = t; b < NBKT; b += 256) {
        int c = cnt[b] - excl[b];
        gbase[b] = (c > 0) ? atomicAdd(&bcnt[b], c) : 0;
    }
    __syncthreads();
    // scatter from registers
    if (vec4) {
#pragma unroll
        for (int it = 0; it < 4; it++) {
            if (!val[it]) continue;
            int ss[4] = {s4[it].x, s4[it].y, s4[it].z, s4[it].w};
            int dd[4] = {d4[it].x, d4[it].y, d4[it].z, d4[it].w};
#pragma unroll
            for (int k = 0; k < 4; k++) {
                int b = dd[k] >> BKT_SHIFT;
                int p = atomicAdd(&curp[b], 1);
                stage[p] = (unsigned)ss[k] | ((unsigned)(dd[k] & (BKT_NODES - 1)) << SRC_SHIFT);
                stageB[p] = (unsigned short)b;
            }
        }
    } else {
        for (int i = t; i < CHUNK; i += 256) {
            int e = e0 + i;
            if (e >= E) break;
            int s = ei[e], d = ei[E + e];
            int b = d >> BKT_SHIFT;
            int p = atomicAdd(&curp[b], 1);
            stage[p] = (unsigned)s | ((unsigned)(d & (BKT_NODES - 1)) << SRC_SHIFT);
            stageB[p] = (unsigned short)b;
        }
    }
    __syncthreads();
    int total = E - e0; if (total > CHUNK) total = CHUNK;
    for (int i = t; i < total; i += 256) {
        int b = stageB[i];
        int idx = gbase[b] + (i - excl[b]);
        if (idx < BKT_CAP) pk[(size_t)b * BKT_CAP + idx] = stage[i];
    }
}

// ---------------- CSR build, phase B: per-bucket counting sort (int4 stash) ----------------
__global__ void k_build(const unsigned int* __restrict__ pk, const int* __restrict__ bcnt,
                        int* __restrict__ rs, int* __restrict__ cur,
                        int* __restrict__ ssrc, int N)
{
    __shared__ unsigned int vals[BKT_CAP];
    __shared__ int cnt[BKT_NODES];
    __shared__ int cursor[BKT_NODES];
    __shared__ int orig[BKT_NODES];
    __shared__ int red[256];
    int b = blockIdx.x;
    int t = threadIdx.x;
    int nb = min(bcnt[b], BKT_CAP);

    int part = 0;
    for (int i = t; i < b; i += 256) part += min(bcnt[i], BKT_CAP);
    red[t] = part;
    cnt[t] = 0;
    __syncthreads();
    for (int off = 128; off; off >>= 1) {
        if (t < off) red[t] += red[t + off];
        __syncthreads();
    }
    int bs = red[0];

    const unsigned int* mypk = pk + (size_t)b * BKT_CAP;
    int nb4 = nb & ~3;
    for (int e = t * 4; e < nb4; e += 1024) {
        uint4 v = *(const uint4*)(mypk + e);
        *(uint4*)(vals + e) = v;
        atomicAdd(&cnt[v.x >> SRC_SHIFT], 1);
        atomicAdd(&cnt[v.y >> SRC_SHIFT], 1);
        atomicAdd(&cnt[v.z >> SRC_SHIFT], 1);
        atomicAdd(&cnt[v.w >> SRC_SHIFT], 1);
    }
    for (int e = nb4 + t; e < nb; e += 256) {
        unsigned int v = mypk[e];
        vals[e] = v;
        atomicAdd(&cnt[v >> SRC_SHIFT], 1);
    }
    __syncthreads();
    orig[t] = cnt[t];
    __syncthreads();
    for (int off = 1; off < BKT_NODES; off <<= 1) {
        int v = (t >= off) ? cnt[t - off] : 0;
        __syncthreads();
        cnt[t] += v;
        __syncthreads();
    }
    {
        int c = orig[t];
        int ex = cnt[t] - c;
        cursor[t] = ex;
        int node = (b << BKT_SHIFT) + t;
        if (node < N) { rs[node] = bs + ex; cur[node] = bs + ex + c; }
    }
    __syncthreads();
    for (int e = t; e < nb; e += 256) {
        unsigned int w = vals[e];
        int p = atomicAdd(&cursor[w >> SRC_SHIFT], 1);
        ssrc[bs + p] = (int)(w & SRC_MASK);
    }
}

// ---------------- Gather layer 1 (pipelined, packed-fp16 accumulate -> h2 fp16) ----------------
__global__ void k_gather1(const int* __restrict__ rs, const int* __restrict__ cur,
                          const int* __restrict__ ssrc, const float4* __restrict__ h4,
                          const float* __restrict__ als1, const float* __restrict__ ald1,
                          const float* __restrict__ b1, float4* __restrict__ h2h4, int N)
{
    int node = blockIdx.x * 4 + (threadIdx.x >> 6);
    if (node >= N) return;
    int l = threadIdx.x & 63;
    int eg = l >> 3;
    int ch = l & 7;
    int head = ch >> 2;
    float ad = ald1[node * 2 + head];

    int beg = rs[node], end = cur[node];
    int cnt = end - beg;
    __half2 acc2[4];
    acc2[0] = acc2[1] = acc2[2] = acc2[3] = __float2half2_rn(0.f);
    float wsum = 0.f;

    // prefetched indices for iteration 0
    int s0n = (eg < cnt) ? ssrc[beg + eg] : node;
    int s1n = (8 + eg < cnt) ? ssrc[beg + 8 + eg] : node;

    for (int base = 0; base < cnt; base += 16) {
        int s0 = s0n, s1 = s1n;
        bool v0 = (base + eg) < cnt, v1 = (base + 8 + eg) < cnt;
        // prefetch next iteration's indices
        int n0 = base + 16 + eg, n1 = base + 24 + eg;
        s0n = (n0 < cnt) ? ssrc[beg + n0] : node;
        s1n = (n1 < cnt) ? ssrc[beg + n1] : node;

        float al0 = als1[s0 * 2 + head];
        float al1 = als1[s1 * 2 + head];
        float4 r0 = h4[(size_t)s0 * 8 + ch];
        float4 r1 = h4[(size_t)s1 * 8 + ch];
        float lg0 = al0 + ad; lg0 = (lg0 >= 0.f) ? lg0 : NEG_SLOPE * lg0;
        float lg1 = al1 + ad; lg1 = (lg1 >= 0.f) ? lg1 : NEG_SLOPE * lg1;
        float w0 = v0 ? __expf(lg0) : 0.f;
        float w1 = v1 ? __expf(lg1) : 0.f;
        __half2 wh0 = __float2half2_rn(w0);
        __half2 wh1 = __float2half2_rn(w1);
        const __half2* p0 = (const __half2*)&r0;
        const __half2* p1 = (const __half2*)&r1;
#pragma unroll
        for (int q = 0; q < 4; q++) {
            acc2[q] = __hfma2(p0[q], wh0, acc2[q]);
            acc2[q] = __hfma2(p1[q], wh1, acc2[q]);
        }
        wsum += w0 + w1;
    }
    float acc[8];
#pragma unroll
    for (int q = 0; q < 4; q++) {
        float2 f = __half22float2(acc2[q]);
        acc[2*q] = f.x; acc[2*q+1] = f.y;
    }
#pragma unroll
    for (int m = 8; m <= 32; m <<= 1) {
        wsum += __shfl_xor(wsum, m);
#pragma unroll
        for (int q = 0; q < 8; q++) acc[q] += __shfl_xor(acc[q], m);
    }
    // self loop (fp32)
    {
        float lg = als1[node * 2 + head] + ad;
        lg = (lg >= 0.f) ? lg : NEG_SLOPE * lg;
        float w = __expf(lg);
        float4 r = h4[(size_t)node * 8 + ch];
        const __half2* p = (const __half2*)&r;
#pragma unroll
        for (int q = 0; q < 4; q++) {
            float2 f = __half22float2(p[q]);
            acc[2*q] += w * f.x; acc[2*q+1] += w * f.y;
        }
        wsum += w;
    }
    float inv = 1.f / (wsum + 1e-16f);
    if (eg == 0) {
        union { float4 f4; __half2 h2[4]; } u;
#pragma unroll
        for (int q = 0; q < 4; q++) {
            float v0 = fmaxf(acc[2*q]   * inv + b1[ch * 8 + 2*q],     0.f);
            float v1 = fmaxf(acc[2*q+1] * inv + b1[ch * 8 + 2*q + 1], 0.f);
            u.h2[q] = __floats2half2_rn(v0, v1);
        }
        h2h4[(size_t)node * 8 + ch] = u.f4;
    }
}

// ---------------- MFMA projection: h3 = h2 @ W2 (fp16 in, fp32 acc) + logits ----------------
__global__ __launch_bounds__(256) void k_node2m(
        const _Float16* __restrict__ h2h, const float* __restrict__ W2,
        const float* __restrict__ a_src2, const float* __restrict__ a_dst2,
        _Float16* __restrict__ h3h, float* __restrict__ als2, float* __restrict__ ald2, int N)
{
    __shared__ _Float16 w2t[64][72];
    __shared__ float h3t[4][16][65];
    int t = threadIdx.x;
    for (int e = t; e < 4096; e += 256) {
        int k = e >> 6, n = e & 63;
        w2t[n][k] = (_Float16)W2[e];
    }
    __syncthreads();

    int w = t >> 6, l = t & 63;
    int l15 = l & 15, quad = l >> 4;
    int nodebase = blockIdx.x * 64 + w * 16;

    int arow = nodebase + l15;
    if (arow >= N) arow = N - 1;
    const half8* ap = (const half8*)(h2h + (size_t)arow * 64 + quad * 8);
    half8 a0 = ap[0];
    half8 a1 = ap[4];
    float4v accs[4];
#pragma unroll
    for (int nt = 0; nt < 4; nt++) {
        half8 b0 = *(const half8*)(&w2t[nt * 16 + l15][quad * 8]);
        half8 b1 = *(const half8*)(&w2t[nt * 16 + l15][32 + quad * 8]);
        float4v c = {0.f, 0.f, 0.f, 0.f};
        c = __builtin_amdgcn_mfma_f32_16x16x32_f16(a0, b0, c, 0, 0, 0);
        c = __builtin_amdgcn_mfma_f32_16x16x32_f16(a1, b1, c, 0, 0, 0);
        accs[nt] = c;
    }
#pragma unroll
    for (int nt = 0; nt < 4; nt++)
#pragma unroll
        for (int r = 0; r < 4; r++)
            h3t[w][quad * 4 + r][nt * 16 + l15] = accs[nt][r];
    __syncthreads();

    int m = l >> 2, part = l & 3;
    int g = blockIdx.x * 64 + w * 16 + m;
    float ps = 0.f, pd = 0.f;
    union { float4 f4[2]; _Float16 h[16]; } u;
#pragma unroll
    for (int c = 0; c < 16; c++) {
        float v = h3t[w][m][part * 16 + c];
        ps += v * a_src2[part * 16 + c];
        pd += v * a_dst2[part * 16 + c];
        u.h[c] = (_Float16)v;
    }
    if (g < N) {
        float4* dst = (float4*)(h3h + (size_t)g * 64) + part * 2;
        dst[0] = u.f4[0];
        dst[1] = u.f4[1];
    }
    ps += __shfl_xor(ps, 1); ps += __shfl_xor(ps, 2);
    pd += __shfl_xor(pd, 1); pd += __shfl_xor(pd, 2);
    if (part == 0 && g < N) { als2[g] = ps; ald2[g] = pd; }
}

// ---------------- Gather layer 2 (pipelined, packed-fp16) + LayerNorm ----------------
__global__ void k_gather2(const int* __restrict__ rs, const int* __restrict__ cur,
                          const int* __restrict__ ssrc, const float4* __restrict__ h4,
                          const float* __restrict__ als2, const float* __restrict__ ald2,
                          const float* __restrict__ b2, const float* __restrict__ gamma,
                          const float* __restrict__ beta, float* __restrict__ out, int N)
{
    int node = blockIdx.x * 4 + (threadIdx.x >> 6);
    if (node >= N) return;
    int l = threadIdx.x & 63;
    int eg = l >> 3;
    int ch = l & 7;
    float ad = ald2[node];

    int beg = rs[node], end = cur[node];
    int cnt = end - beg;
    __half2 acc2[4];
    acc2[0] = acc2[1] = acc2[2] = acc2[3] = __float2half2_rn(0.f);
    float wsum = 0.f;

    int s0n = (eg < cnt) ? ssrc[beg + eg] : node;
    int s1n = (8 + eg < cnt) ? ssrc[beg + 8 + eg] : node;

    for (int base = 0; base < cnt; base += 16) {
        int s0 = s0n, s1 = s1n;
        bool v0 = (base + eg) < cnt, v1 = (base + 8 + eg) < cnt;
        int n0 = base + 16 + eg, n1 = base + 24 + eg;
        s0n = (n0 < cnt) ? ssrc[beg + n0] : node;
        s1n = (n1 < cnt) ? ssrc[beg + n1] : node;

        float al0 = als2[s0];
        float al1 = als2[s1];
        float4 r0 = h4[(size_t)s0 * 8 + ch];
        float4 r1 = h4[(size_t)s1 * 8 + ch];
        float lg0 = al0 + ad; lg0 = (lg0 >= 0.f) ? lg0 : NEG_SLOPE * lg0;
        float lg1 = al1 + ad; lg1 = (lg1 >= 0.f) ? lg1 : NEG_SLOPE * lg1;
        float w0 = v0 ? __expf(lg0) : 0.f;
        float w1 = v1 ? __expf(lg1) : 0.f;
        __half2 wh0 = __float2half2_rn(w0);
        __half2 wh1 = __float2half2_rn(w1);
        const __half2* p0 = (const __half2*)&r0;
        const __half2* p1 = (const __half2*)&r1;
#pragma unroll
        for (int q = 0; q < 4; q++) {
            acc2[q] = __hfma2(p0[q], wh0, acc2[q]);
            acc2[q] = __hfma2(p1[q], wh1, acc2[q]);
        }
        wsum += w0 + w1;
    }
    float acc[8];
#pragma unroll
    for (int q = 0; q < 4; q++) {
        float2 f = __half22float2(acc2[q]);
        acc[2*q] = f.x; acc[2*q+1] = f.y;
    }
#pragma unroll
    for (int m = 8; m <= 32; m <<= 1) {
        wsum += __shfl_xor(wsum, m);
#pragma unroll
        for (int q = 0; q < 8; q++) acc[q] += __shfl_xor(acc[q], m);
    }
    // self loop (fp32)
    {
        float lg = als2[node] + ad;
        lg = (lg >= 0.f) ? lg : NEG_SLOPE * lg;
        float w = __expf(lg);
        float4 r = h4[(size_t)node * 8 + ch];
        const __half2* p = (const __half2*)&r;
#pragma unroll
        for (int q = 0; q < 4; q++) {
            float2 f = __half22float2(p[q]);
            acc[2*q] += w * f.x; acc[2*q+1] += w * f.y;
        }
        wsum += w;
    }
    float inv = 1.f / (wsum + 1e-16f);
    float o[8];
    float s = 0.f;
#pragma unroll
    for (int q = 0; q < 8; q++) { o[q] = acc[q] * inv + b2[ch * 8 + q]; s += o[q]; }
#pragma unroll
    for (int m = 1; m <= 4; m <<= 1) s += __shfl_xor(s, m);
    float mu = s * (1.f / 64.f);
    float v = 0.f;
#pragma unroll
    for (int q = 0; q < 8; q++) { float d = o[q] - mu; v += d * d; }
#pragma unroll
    for (int m = 1; m <= 4; m <<= 1) v += __shfl_xor(v, m);
    v *= (1.f / 64.f);
    float r = rsqrtf(v + 1e-5f);
    if (eg == 0) {
        float res[8];
#pragma unroll
        for (int q = 0; q < 8; q++)
            res[q] = (o[q] - mu) * r * gamma[ch * 8 + q] + beta[ch * 8 + q];
        float4* op = (float4*)(out + (size_t)node * 64 + ch * 8);
        op[0] = make_float4(res[0], res[1], res[2], res[3]);
        op[1] = make_float4(res[4], res[5], res[6], res[7]);
    }
}

extern "C" void kernel_launch(void* const* d_in, const int* in_sizes, int n_in,
                              void* d_out, int out_size, void* d_ws, size_t ws_size,
                              hipStream_t stream) {
    const float* x        = (const float*)d_in[0];
    const int*   ei       = (const int*)  d_in[1];
    const int*   type_ids = (const int*)  d_in[2];
    const float* type_emb = (const float*)d_in[3];
    const float* W1       = (const float*)d_in[4];
    const float* a_src1   = (const float*)d_in[5];
    const float* a_dst1   = (const float*)d_in[6];
    const float* b1       = (const float*)d_in[7];
    const float* W2       = (const float*)d_in[8];
    const float* a_src2   = (const float*)d_in[9];
    const float* a_dst2   = (const float*)d_in[10];
    const float* b2       = (const float*)d_in[11];
    const float* gamma    = (const float*)d_in[12];
    const float* beta     = (const float*)d_in[13];

    int N = in_sizes[0] / 5;
    int E = in_sizes[1] / 2;
    int NBKT = (N + BKT_NODES - 1) >> BKT_SHIFT;

    // Workspace: pk (16 MB, dead after k_build) overlaid on h2h/h3h (25.6 MB).
    char* base = (char*)d_ws;
    size_t off = 0;
    auto carve = [&](size_t bytes) { void* p = base + off; off += (bytes + 255) & ~(size_t)255; return p; };
    __half2* h1h = (__half2*)carve((size_t)N * 64 * sizeof(__half));
    size_t pk_bytes = (size_t)NBKT * BKT_CAP * sizeof(unsigned int);
    size_t h23_bytes = 2 * (size_t)N * 64 * sizeof(__half);
    char* uni = (char*)carve(pk_bytes > h23_bytes ? pk_bytes : h23_bytes);
    _Float16* h2h = (_Float16*)uni;
    _Float16* h3h = (_Float16*)(uni + (size_t)N * 64 * sizeof(__half));
    unsigned int* pk = (unsigned int*)uni;
    float* als1  = (float*)carve((size_t)N * 2 * sizeof(float));
    float* ald1  = (float*)carve((size_t)N * 2 * sizeof(float));
    float* als2  = (float*)carve((size_t)N * sizeof(float));
    float* ald2  = (float*)carve((size_t)N * sizeof(float));
    int*   rs    = (int*)carve((size_t)N * sizeof(int));
    int*   cur   = (int*)carve((size_t)N * sizeof(int));
    int*   bcnt  = (int*)carve(1024 * sizeof(int));
    int*   ssrc  = (int*)carve((size_t)E * sizeof(int));

    dim3 tb(256);
    dim3 nb((N + 3) / 4);

    k_node1<<<nb, tb, 0, stream>>>(x, type_ids, type_emb, W1, a_src1, a_dst1,
                                   h1h, als1, ald1, N);

    hipMemsetAsync(bcnt, 0, NBKT * sizeof(int), stream);
    k_bucketA<<<dim3((E + CHUNK - 1) / CHUNK), tb, 0, stream>>>(ei, pk, bcnt, E, NBKT);
    k_build<<<dim3(NBKT), tb, 0, stream>>>(pk, bcnt, rs, cur, ssrc, N);

    k_gather1<<<nb, tb, 0, stream>>>(rs, cur, ssrc, (const float4*)h1h, als1, ald1, b1,
                                     (float4*)h2h, N);
    k_node2m<<<dim3((N + 63) / 64), tb, 0, stream>>>(h2h, W2, a_src2, a_dst2,
                                                     h3h, als2, ald2, N);
    k_gather2<<<nb, tb, 0, stream>>>(rs, cur, ssrc, (const float4*)h3h, als2, ald2, b2,
                                     gamma, beta, (float*)d_out, N);
}